// Round 1
// baseline (1387.325 us; speedup 1.0000x reference)
//
#include <hip/hip_runtime.h>
#include <hip/hip_fp16.h>
#include <math.h>
#include <type_traits>

#define DEVI __device__ __forceinline__

typedef __attribute__((ext_vector_type(8))) short bf16x8;
typedef __attribute__((ext_vector_type(4))) float f32x4;
typedef __attribute__((ext_vector_type(4))) unsigned int u32x4;

DEVI unsigned int pack_bf16(float a, float b) {
  unsigned int ua = __float_as_uint(a), ub = __float_as_uint(b);
  ua = (ua + 0x7FFFu + ((ua >> 16) & 1u)) >> 16;   // RNE
  ub = (ub + 0x7FFFu + ((ub >> 16) & 1u)) >> 16;
  return ua | (ub << 16);
}

// ---------------- GEMM: C[M,N] = A[M,K] * B[N,K]^T  (both K-contiguous, "NT")
// fp32 inputs converted to bf16 in staging; 128x128 tile, BK=64, 4 waves, 64x64/wave.
// XOR-swizzled LDS (byte ^= (row&7)<<4) on write AND read (reg-staged, rule #21 safe).
template<typename OutT, bool BIAS, int SPLIT>
__global__ __launch_bounds__(256) void gee_gemm_nt(
    const float* __restrict__ A, const float* __restrict__ B,
    const float* __restrict__ bias, OutT* __restrict__ C,
    int M, int N, int K)
{
  __shared__ unsigned int AsU[128 * 32];
  __shared__ unsigned int BsU[128 * 32];
  const int tid = threadIdx.x;
  const int bm = blockIdx.y * 128, bn = blockIdx.x * 128;
  const int ksteps = (K + 63) >> 6;
  const int sz = (ksteps + SPLIT - 1) / SPLIT;
  const int kbBeg = (int)blockIdx.z * sz;
  const int kbEnd = min(ksteps, kbBeg + sz);

  const int lane = tid & 63, wv = tid >> 6;
  const int wr = (wv >> 1) * 64, wc = (wv & 1) * 64;
  const int lrow = lane & 15, kg = lane >> 4;

  const f32x4 vzero = {0.f, 0.f, 0.f, 0.f};
  f32x4 acc[4][4];
#pragma unroll
  for (int i = 0; i < 4; ++i)
#pragma unroll
    for (int j = 0; j < 4; ++j) acc[i][j] = vzero;

  const int sr = tid >> 1;          // staging row 0..127
  const int scb = (tid & 1) * 32;   // staging col base (elements)

  for (int kb = kbBeg; kb < kbEnd; ++kb) {
    const int k0 = kb * 64;
    // ---- stage A tile
    {
      const long grow = (long)bm + sr;
      const bool rok = grow < (long)M;
      const float* p = A + (size_t)grow * (size_t)K + k0 + scb;
      unsigned int u[16];
#pragma unroll
      for (int i = 0; i < 8; ++i) {
        float4 f = make_float4(0.f, 0.f, 0.f, 0.f);
        if (rok && (k0 + scb + i * 4 + 3) < K) f = *(const float4*)(p + i * 4);
        u[i * 2]     = pack_bf16(f.x, f.y);
        u[i * 2 + 1] = pack_bf16(f.z, f.w);
      }
#pragma unroll
      for (int j = 0; j < 4; ++j) {
        int byte0 = (scb * 2 + j * 16) ^ ((sr & 7) << 4);
        *(u32x4*)&AsU[sr * 32 + (byte0 >> 2)] = *(u32x4*)&u[j * 4];
      }
    }
    // ---- stage B tile
    {
      const long grow = (long)bn + sr;
      const bool rok = grow < (long)N;
      const float* p = B + (size_t)grow * (size_t)K + k0 + scb;
      unsigned int u[16];
#pragma unroll
      for (int i = 0; i < 8; ++i) {
        float4 f = make_float4(0.f, 0.f, 0.f, 0.f);
        if (rok && (k0 + scb + i * 4 + 3) < K) f = *(const float4*)(p + i * 4);
        u[i * 2]     = pack_bf16(f.x, f.y);
        u[i * 2 + 1] = pack_bf16(f.z, f.w);
      }
#pragma unroll
      for (int j = 0; j < 4; ++j) {
        int byte0 = (scb * 2 + j * 16) ^ ((sr & 7) << 4);
        *(u32x4*)&BsU[sr * 32 + (byte0 >> 2)] = *(u32x4*)&u[j * 4];
      }
    }
    __syncthreads();
#pragma unroll
    for (int kk = 0; kk < 2; ++kk) {
      const int kbyte = kk * 64 + kg * 16;
      bf16x8 af[4], bfv[4];
#pragma unroll
      for (int i = 0; i < 4; ++i) {
        int ar = wr + i * 16 + lrow;
        af[i] = *(const bf16x8*)&AsU[ar * 32 + ((kbyte ^ ((ar & 7) << 4)) >> 2)];
        int br = wc + i * 16 + lrow;
        bfv[i] = *(const bf16x8*)&BsU[br * 32 + ((kbyte ^ ((br & 7) << 4)) >> 2)];
      }
#pragma unroll
      for (int i = 0; i < 4; ++i)
#pragma unroll
        for (int j = 0; j < 4; ++j)
          acc[i][j] = __builtin_amdgcn_mfma_f32_16x16x32_bf16(af[i], bfv[j], acc[i][j], 0, 0, 0);
    }
    __syncthreads();
  }

  const size_t zoff = (SPLIT > 1) ? (size_t)blockIdx.z * (size_t)M * (size_t)N : 0;
#pragma unroll
  for (int i = 0; i < 4; ++i) {
#pragma unroll
    for (int j = 0; j < 4; ++j) {
      const int col = bn + wc + j * 16 + lrow;
      if (col >= N) continue;
      const int row0 = bm + wr + i * 16 + kg * 4;
      float bv = BIAS ? bias[col] : 0.f;
#pragma unroll
      for (int r = 0; r < 4; ++r) {
        const int gr = row0 + r;
        if (gr < M) {
          float v = acc[i][j][r] + bv;
          if constexpr (std::is_same<OutT, __half>::value)
            C[zoff + (size_t)gr * (size_t)N + col] = __float2half(v);
          else
            C[zoff + (size_t)gr * (size_t)N + col] = v;
        }
      }
    }
  }
}

// ---------------- fused: sum split-K partials + bias + LayerNorm + exact GELU + l2norm
__global__ __launch_bounds__(256) void gee_fuse_ln1(
    const float* __restrict__ P, const float* __restrict__ b_enc,
    const float* __restrict__ g1, const float* __restrict__ b1,
    float* __restrict__ hx)
{
  const int row = blockIdx.x, tid = threadIdx.x;
  __shared__ float red[16];
  const size_t MN = (size_t)4096 * 512;
  float v[2];
#pragma unroll
  for (int e = 0; e < 2; ++e) {
    const int c = tid + e * 256;
    const size_t o = (size_t)row * 512 + c;
    v[e] = P[o] + P[MN + o] + P[2 * MN + o] + P[3 * MN + o] + b_enc[c];
  }
  float a = v[0] + v[1];
  float b = v[0] * v[0] + v[1] * v[1];
#pragma unroll
  for (int o = 32; o > 0; o >>= 1) { a += __shfl_xor(a, o); b += __shfl_xor(b, o); }
  const int lane = tid & 63, wvi = tid >> 6;
  if (lane == 0) { red[wvi] = a; red[8 + wvi] = b; }
  __syncthreads();
  const float mu  = (red[0] + red[1] + red[2] + red[3]) * (1.f / 512.f);
  const float ex2 = (red[8] + red[9] + red[10] + red[11]) * (1.f / 512.f);
  const float inv = rsqrtf(ex2 - mu * mu + 1e-5f);
  float gl[2], ss = 0.f;
#pragma unroll
  for (int e = 0; e < 2; ++e) {
    const int c = tid + e * 256;
    const float y = (v[e] - mu) * inv * g1[c] + b1[c];
    const float t = 0.5f * y * (1.f + erff(y * 0.70710678118654752f));
    gl[e] = t; ss += t * t;
  }
  __syncthreads();
#pragma unroll
  for (int o = 32; o > 0; o >>= 1) ss += __shfl_xor(ss, o);
  if (lane == 0) red[wvi] = ss;
  __syncthreads();
  const float nrm = sqrtf(red[0] + red[1] + red[2] + red[3]);
  const float sc = 1.f / fmaxf(nrm, 1e-12f);
#pragma unroll
  for (int e = 0; e < 2; ++e)
    hx[(size_t)row * 512 + tid + e * 256] = gl[e] * sc;
}

// ---------------- in-place row l2norm of e [20000,512]
__global__ __launch_bounds__(256) void gee_l2rows(float* __restrict__ e)
{
  const int row = blockIdx.x, tid = threadIdx.x;
  __shared__ float red[8];
  const size_t o = (size_t)row * 512;
  const float v0 = e[o + tid], v1 = e[o + tid + 256];
  float ss = v0 * v0 + v1 * v1;
#pragma unroll
  for (int w = 32; w > 0; w >>= 1) ss += __shfl_xor(ss, w);
  if ((tid & 63) == 0) red[tid >> 6] = ss;
  __syncthreads();
  const float sc = 1.f / fmaxf(sqrtf(red[0] + red[1] + red[2] + red[3]), 1e-12f);
  e[o + tid] = v0 * sc;
  e[o + tid + 256] = v1 * sc;
}

// ---------------- per-row top-64 (radix select on fp16 keys) + softmax over selected
__global__ __launch_bounds__(256) void gee_topk(
    const __half* __restrict__ scores, int* __restrict__ oidx, float* __restrict__ ow)
{
  const int row = blockIdx.x, tid = threadIdx.x;
  const int G = 20000;
  const __half* srow = scores + (size_t)row * G;
  __shared__ unsigned short keys[20000];
  __shared__ int hist[256];
  __shared__ int sel[64];
  __shared__ int tie[128];
  __shared__ int s_n1, s_n2, s_hb, s_cg, s_kthr;

  for (int i = tid; i < G; i += 256) {
    const unsigned short raw = ((const unsigned short*)srow)[i];
    keys[i] = (raw & 0x8000) ? (unsigned short)(~raw) : (unsigned short)(raw | 0x8000);
  }
  if (tid < 256) hist[tid] = 0;
  __syncthreads();
  for (int i = tid; i < G; i += 256) atomicAdd(&hist[keys[i] >> 8], 1);
  __syncthreads();
  if (tid == 0) {
    int run = 0;
    for (int b = 255; b >= 0; --b) {
      run += hist[b];
      if (run >= 64) { s_hb = b; s_cg = run - hist[b]; break; }
    }
  }
  __syncthreads();
  const int hb = s_hb, cg = s_cg;
  if (tid < 256) hist[tid] = 0;
  __syncthreads();
  for (int i = tid; i < G; i += 256) {
    const int k = keys[i];
    if ((k >> 8) == hb) atomicAdd(&hist[k & 255], 1);
  }
  __syncthreads();
  if (tid == 0) {
    int run = cg;
    for (int b = 255; b >= 0; --b) {
      run += hist[b];
      if (run >= 64) { s_kthr = (hb << 8) | b; break; }
    }
    s_n1 = 0; s_n2 = 0;
  }
  __syncthreads();
  const int kthr = s_kthr;
  for (int i = tid; i < G; i += 256) {
    const int k = keys[i];
    if (k > kthr) { const int p = atomicAdd(&s_n1, 1); sel[p] = i; }
    else if (k == kthr) { const int p = atomicAdd(&s_n2, 1); if (p < 128) tie[p] = i; }
  }
  __syncthreads();
  if (tid == 0) {
    const int n1 = s_n1;
    const int n2 = min(s_n2, 128);
    const int need = 64 - n1;
    for (int r = 0; r < need; ++r) {           // smallest indices first (top_k tie-break)
      int best = 1 << 30, bj = 0;
      for (int j = 0; j < n2; ++j)
        if (tie[j] < best) { best = tie[j]; bj = j; }
      sel[n1 + r] = best;
      tie[bj] = 1 << 30;
    }
  }
  __syncthreads();
  if (tid < 64) {
    const int idx = sel[tid];
    const float s = __half2float(srow[idx]) * 10.0f;   // 1/T
    float m = s;
#pragma unroll
    for (int o = 32; o > 0; o >>= 1) m = fmaxf(m, __shfl_xor(m, o));
    const float w = __expf(s - m);
    float d = w;
#pragma unroll
    for (int o = 32; o > 0; o >>= 1) d += __shfl_xor(d, o);
    oidx[(size_t)row * 64 + tid] = idx;
    ow[(size_t)row * 64 + tid] = w / d;
  }
}

// ---------------- ctx[b] = sum_k attn_k * e[idx_k]
__global__ __launch_bounds__(256) void gee_ctx(
    const int* __restrict__ idx, const float* __restrict__ w,
    const float* __restrict__ e, float* __restrict__ ctx)
{
  const int row = blockIdx.x, tid = threadIdx.x;
  __shared__ int sidx[64];
  __shared__ float sw[64];
  if (tid < 64) { sidx[tid] = idx[(size_t)row * 64 + tid]; sw[tid] = w[(size_t)row * 64 + tid]; }
  __syncthreads();
  float a0 = 0.f, a1 = 0.f;
#pragma unroll 4
  for (int k = 0; k < 64; ++k) {
    const float* er = e + (size_t)sidx[k] * 512;
    const float wk = sw[k];
    a0 += wk * er[tid];
    a1 += wk * er[tid + 256];
  }
  ctx[(size_t)row * 512 + tid] = a0;
  ctx[(size_t)row * 512 + tid + 256] = a1;
}

// ---------------- h_cell = (1+gamma)*h_x + beta
__global__ __launch_bounds__(256) void gee_film(
    const float4* __restrict__ gm, const float4* __restrict__ bt,
    const float4* __restrict__ hx, float4* __restrict__ hc, int n4)
{
  const int i = blockIdx.x * 256 + threadIdx.x;
  if (i < n4) {
    const float4 g = gm[i], b = bt[i], h = hx[i];
    float4 r;
    r.x = (1.f + g.x) * h.x + b.x;
    r.y = (1.f + g.y) * h.y + b.y;
    r.z = (1.f + g.z) * h.z + b.z;
    r.w = (1.f + g.w) * h.w + b.w;
    hc[i] = r;
  }
}

// ---------------- LN2 + exact GELU -> out [4096,1024]
__global__ __launch_bounds__(256) void gee_ln2(
    const float* __restrict__ h2, const float* __restrict__ g2,
    const float* __restrict__ b2, float* __restrict__ out)
{
  const int row = blockIdx.x, tid = threadIdx.x;
  __shared__ float red[16];
  float v[4];
  float a = 0.f, b = 0.f;
#pragma unroll
  for (int e = 0; e < 4; ++e) {
    v[e] = h2[(size_t)row * 1024 + tid + e * 256];
    a += v[e]; b += v[e] * v[e];
  }
#pragma unroll
  for (int o = 32; o > 0; o >>= 1) { a += __shfl_xor(a, o); b += __shfl_xor(b, o); }
  const int lane = tid & 63, wvi = tid >> 6;
  if (lane == 0) { red[wvi] = a; red[8 + wvi] = b; }
  __syncthreads();
  const float mu  = (red[0] + red[1] + red[2] + red[3]) * (1.f / 1024.f);
  const float ex2 = (red[8] + red[9] + red[10] + red[11]) * (1.f / 1024.f);
  const float inv = rsqrtf(ex2 - mu * mu + 1e-5f);
#pragma unroll
  for (int e = 0; e < 4; ++e) {
    const int c = tid + e * 256;
    const float y = (v[e] - mu) * inv * g2[c] + b2[c];
    out[(size_t)row * 1024 + c] = 0.5f * y * (1.f + erff(y * 0.70710678118654752f));
  }
}

extern "C" void kernel_launch(void* const* d_in, const int* in_sizes, int n_in,
                              void* d_out, int out_size, void* d_ws, size_t ws_size,
                              hipStream_t stream)
{
  const float* x       = (const float*)d_in[0];
  const float* g       = (const float*)d_in[1];
  const float* W_enc   = (const float*)d_in[2];
  const float* b_enc   = (const float*)d_in[3];
  const float* ln1_g   = (const float*)d_in[4];
  const float* ln1_b   = (const float*)d_in[5];
  const float* W_ga    = (const float*)d_in[6];
  const float* W_gamma = (const float*)d_in[7];
  const float* b_gamma = (const float*)d_in[8];
  const float* W_beta  = (const float*)d_in[9];
  const float* b_beta  = (const float*)d_in[10];
  const float* W_exp   = (const float*)d_in[11];
  const float* b_exp   = (const float*)d_in[12];
  const float* ln2_g   = (const float*)d_in[13];
  const float* ln2_b   = (const float*)d_in[14];
  float* out = (float*)d_out;

  char* ws = (char*)d_ws;
  // Region 0 (0..163.84MB) is time-shared: split-K partials -> fp16 scores -> gamma/beta/h_cell/h2
  constexpr size_t OFF_PART   = 0;          // 4*4096*512*4  = 33,554,432   (steps 1-2)
  constexpr size_t OFF_SCORES = 0;          // 4096*20000*2  = 163,840,000  (steps 5-6)
  constexpr size_t OFF_GA     = 0;          // 8,388,608                    (steps 8-9)
  constexpr size_t OFF_BE     = 8388608;    // 8,388,608
  constexpr size_t OFF_HC     = 16777216;   // 8,388,608
  constexpr size_t OFF_H2     = 25165824;   // 16,777,216
  constexpr size_t OFF_E      = 163840000;  // 40,960,000
  constexpr size_t OFF_HX     = 204800000;  // 8,388,608
  constexpr size_t OFF_CTX    = 213188608;  // 8,388,608
  constexpr size_t OFF_IDX    = 221577216;  // 1,048,576
  constexpr size_t OFF_W      = 222625792;  // 1,048,576  -> total 223,674,368 bytes

  float*  part   = (float*)(ws + OFF_PART);
  __half* scores = (__half*)(ws + OFF_SCORES);
  float*  ga     = (float*)(ws + OFF_GA);
  float*  be     = (float*)(ws + OFF_BE);
  float*  hc     = (float*)(ws + OFF_HC);
  float*  h2     = (float*)(ws + OFF_H2);
  float*  e      = (float*)(ws + OFF_E);
  float*  hx     = (float*)(ws + OFF_HX);
  float*  ctx    = (float*)(ws + OFF_CTX);
  int*    tidx   = (int*)(ws + OFF_IDX);
  float*  tw     = (float*)(ws + OFF_W);

  // 1) split-K=4 partials of x @ W_enc^T  [4][4096][512]
  gee_gemm_nt<float, false, 4><<<dim3(4, 32, 4), 256, 0, stream>>>(x, W_enc, nullptr, part, 4096, 512, 20000);
  // 2) h_x = l2norm(gelu(LN1(sum partials + b_enc)))
  gee_fuse_ln1<<<4096, 256, 0, stream>>>(part, b_enc, ln1_g, ln1_b, hx);
  // 3) e_raw = g @ W_ga^T  [20000][512]
  gee_gemm_nt<float, false, 1><<<dim3(4, 157, 1), 256, 0, stream>>>(g, W_ga, nullptr, e, 20000, 512, 512);
  // 4) e = l2norm rows (in place)
  gee_l2rows<<<20000, 256, 0, stream>>>(e);
  // 5) scores = h_x @ e^T  (fp16 out, raw cosine; /T applied in topk)
  gee_gemm_nt<__half, false, 1><<<dim3(157, 32, 1), 256, 0, stream>>>(hx, e, nullptr, scores, 4096, 20000, 512);
  // 6) top-64 + softmax weights
  gee_topk<<<4096, 256, 0, stream>>>(scores, tidx, tw);
  // 7) ctx = attn-weighted sum of e rows
  gee_ctx<<<4096, 256, 0, stream>>>(tidx, tw, e, ctx);
  // 8) FiLM gamma / beta
  gee_gemm_nt<float, true, 1><<<dim3(4, 32, 1), 256, 0, stream>>>(ctx, W_gamma, b_gamma, ga, 4096, 512, 512);
  gee_gemm_nt<float, true, 1><<<dim3(4, 32, 1), 256, 0, stream>>>(ctx, W_beta, b_beta, be, 4096, 512, 512);
  // 9) h_cell = (1+gamma)*h_x + beta
  gee_film<<<2048, 256, 0, stream>>>((const float4*)ga, (const float4*)be, (const float4*)hx, (float4*)hc, 524288);
  // 10) h2 = h_cell @ W_exp^T + b_exp  [4096][1024]
  gee_gemm_nt<float, true, 1><<<dim3(8, 32, 1), 256, 0, stream>>>(hc, W_exp, b_exp, h2, 4096, 1024, 512);
  // 11) out = gelu(LN2(h2))
  gee_ln2<<<4096, 256, 0, stream>>>(h2, ln2_g, ln2_b, out);
}

// Round 2
// 1181.895 us; speedup vs baseline: 1.1738x; 1.1738x over previous
//
#include <hip/hip_runtime.h>
#include <hip/hip_fp16.h>
#include <math.h>
#include <type_traits>

#define DEVI __device__ __forceinline__

typedef __attribute__((ext_vector_type(8))) short bf16x8;
typedef __attribute__((ext_vector_type(4))) float f32x4;
typedef __attribute__((ext_vector_type(4))) unsigned int u32x4;
typedef unsigned short ushort_t;

DEVI unsigned int pack_bf16(float a, float b) {
  unsigned int ua = __float_as_uint(a), ub = __float_as_uint(b);
  ua = (ua + 0x7FFFu + ((ua >> 16) & 1u)) >> 16;   // RNE
  ub = (ub + 0x7FFFu + ((ub >> 16) & 1u)) >> 16;
  return ua | (ub << 16);
}

DEVI bf16x8 cvt_bf16x8(f32x4 lo, f32x4 hi) {
  unsigned int r0, r1, r2, r3;
  asm("v_cvt_pk_bf16_f32 %0, %1, %2" : "=v"(r0) : "v"(lo[0]), "v"(lo[1]));
  asm("v_cvt_pk_bf16_f32 %0, %1, %2" : "=v"(r1) : "v"(lo[2]), "v"(lo[3]));
  asm("v_cvt_pk_bf16_f32 %0, %1, %2" : "=v"(r2) : "v"(hi[0]), "v"(hi[1]));
  asm("v_cvt_pk_bf16_f32 %0, %1, %2" : "=v"(r3) : "v"(hi[2]), "v"(hi[3]));
  union { u32x4 u; bf16x8 v; } x;
  x.u = u32x4{r0, r1, r2, r3};
  return x.v;
}

// =======================================================================
// GEMM: C[M,N](+=bias) = A_fp32[M,K] * B_bf16[N,K]^T
// 128x128 tile, BK=64, 4 waves (64x64/wave).
// A staged fp32 via global_load_lds (32KB, swizzled byte^=(row&7)<<5),
// B staged bf16 via global_load_lds (16KB, swizzled byte^=(row&7)<<4).
// Swizzle realized as: linear LDS dest + pre-swizzled GLOBAL source +
// swizzled ds_read (rule #21). A converted to bf16 at frag read (v_cvt_pk).
// SPLITZ>1: blockIdx z = K-split slice, C gets z*M*N offset (partials).
// DUALB: z in {0,1} selects (B0,bias0)/(B1,bias1), C offset z*M*N.
// =======================================================================
template<int SPLITZ, bool DUALB, bool BIAS, typename OutT>
__global__ __launch_bounds__(256, 3) void bgemm(
    const float* __restrict__ A, const ushort_t* __restrict__ B0,
    const ushort_t* __restrict__ B1, const float* __restrict__ bias0,
    const float* __restrict__ bias1, OutT* __restrict__ C,
    int M, int N, int K, int nbn, int nbm)
{
  __shared__ __align__(16) float    As[32 * 256];   // 32 KB
  __shared__ __align__(16) ushort_t Bs[16 * 512];   // 16 KB
  const int tid = threadIdx.x, lane = tid & 63, wv = tid >> 6;

  // bijective XCD remap of flat block id (m204)
  const int nwg = gridDim.x;
  const int hw = blockIdx.x;
  const int q = nwg >> 3, r = nwg & 7;
  const int xcd = hw & 7, pos = hw >> 3;
  const int lid = (xcd < r ? xcd * (q + 1) : r * (q + 1) + (xcd - r) * q) + pos;
  const int bn = lid % nbn;
  const int t2 = lid / nbn;
  const int bm = t2 % nbm;
  const int z  = t2 / nbm;

  const ushort_t* B  = (DUALB && z == 1) ? B1 : B0;
  const float* bias  = (DUALB && z == 1) ? bias1 : bias0;

  const int ksteps = (K + 63) >> 6;
  int kbBeg = 0, kbEnd = ksteps;
  if (SPLITZ > 1) {
    const int sz = (ksteps + SPLITZ - 1) / SPLITZ;
    kbBeg = z * sz;
    kbEnd = min(ksteps, kbBeg + sz);
  }

  const int wr = (wv >> 1) * 64, wc = (wv & 1) * 64;
  const int lrow = lane & 15, kg = lane >> 4;

  f32x4 acc[4][4];
#pragma unroll
  for (int i = 0; i < 4; ++i)
#pragma unroll
    for (int j = 0; j < 4; ++j) acc[i][j] = f32x4{0.f, 0.f, 0.f, 0.f};

  // staging addressing (pre-swizzled source columns)
  const int rA0  = wv * 4 + (lane >> 4);                                  // + j*16
  const int colA = (((lane & 15) << 4) ^ ((rA0 & 7) << 5)) >> 2;          // float idx in [0,64)
  const int rB0  = wv * 8 + (lane >> 3);                                  // + j*32
  const int colB = (((lane & 7) << 4) ^ ((rB0 & 7) << 4)) >> 1;           // bf16 idx in [0,64)

  const float* aSrc[8];
#pragma unroll
  for (int j = 0; j < 8; ++j) {
    const int grow = min(bm * 128 + rA0 + j * 16, M - 1);
    aSrc[j] = A + (size_t)grow * (size_t)K + colA;
  }
  const ushort_t* bSrc[4];
#pragma unroll
  for (int j = 0; j < 4; ++j) {
    const int grow = min(bn * 128 + rB0 + j * 32, N - 1);
    bSrc[j] = B + (size_t)grow * (size_t)K + colB;
  }

  for (int kb = kbBeg; kb < kbEnd; ++kb) {
    const int k0 = kb << 6;
    if (k0 + 64 <= K) {
      // fast path: async DMA, no staging VGPRs
#pragma unroll
      for (int j = 0; j < 8; ++j)
        __builtin_amdgcn_global_load_lds(
            (const __attribute__((address_space(1))) void*)(aSrc[j] + k0),
            (__attribute__((address_space(3))) void*)&As[(j * 4 + wv) * 256], 16, 0, 0);
#pragma unroll
      for (int j = 0; j < 4; ++j)
        __builtin_amdgcn_global_load_lds(
            (const __attribute__((address_space(1))) void*)(bSrc[j] + k0),
            (__attribute__((address_space(3))) void*)&Bs[(j * 4 + wv) * 512], 16, 0, 0);
    } else {
      // K-tail: reg-staged, zero-filled (K % 8 == 0 so 16B granules suffice)
#pragma unroll
      for (int j = 0; j < 8; ++j) {
        float4 f = make_float4(0.f, 0.f, 0.f, 0.f);
        if (k0 + colA + 4 <= K) f = *(const float4*)(aSrc[j] + k0);
        *(float4*)((char*)As + (j * 4 + wv) * 1024 + lane * 16) = f;
      }
#pragma unroll
      for (int j = 0; j < 4; ++j) {
        u32x4 v = {0u, 0u, 0u, 0u};
        if (k0 + colB + 8 <= K) v = *(const u32x4*)(bSrc[j] + k0);
        *(u32x4*)((char*)Bs + (j * 4 + wv) * 1024 + lane * 16) = v;
      }
    }
    __syncthreads();
#pragma unroll
    for (int kk = 0; kk < 2; ++kk) {
      bf16x8 af[4], bfr[4];
#pragma unroll
      for (int i = 0; i < 4; ++i) {
        const int ra = wr + i * 16 + lrow;
        const int ab = (kk * 128 + (kg << 5)) ^ ((ra & 7) << 5);
        const char* pa = (const char*)As + ra * 256 + ab;
        af[i] = cvt_bf16x8(*(const f32x4*)pa, *(const f32x4*)(pa + 16));
        const int rb = wc + i * 16 + lrow;
        const int bb = (kk * 64 + (kg << 4)) ^ ((rb & 7) << 4);
        bfr[i] = *(const bf16x8*)((const char*)Bs + rb * 128 + bb);
      }
#pragma unroll
      for (int i = 0; i < 4; ++i)
#pragma unroll
        for (int j = 0; j < 4; ++j)
          acc[i][j] = __builtin_amdgcn_mfma_f32_16x16x32_bf16(af[i], bfr[j], acc[i][j], 0, 0, 0);
    }
    __syncthreads();
  }

  const size_t zoff = (SPLITZ > 1 || DUALB) ? (size_t)z * (size_t)M * (size_t)N : 0;
#pragma unroll
  for (int i = 0; i < 4; ++i) {
#pragma unroll
    for (int j = 0; j < 4; ++j) {
      const int col = bn * 128 + wc + j * 16 + lrow;
      if (col >= N) continue;
      const int row0 = bm * 128 + wr + i * 16 + kg * 4;
      float bv = 0.f;
      if (BIAS) bv = bias[col];
#pragma unroll
      for (int rr = 0; rr < 4; ++rr) {
        const int gr = row0 + rr;
        if (gr < M) {
          const float v = acc[i][j][rr] + bv;
          if constexpr (std::is_same<OutT, __half>::value)
            C[zoff + (size_t)gr * (size_t)N + col] = __float2half(v);
          else
            C[zoff + (size_t)gr * (size_t)N + col] = v;
        }
      }
    }
  }
}

// ---------------- fp32 -> bf16 convert (8 elems/thread)
__global__ __launch_bounds__(256) void f2b(
    const float4* __restrict__ in, u32x4* __restrict__ out, int n8)
{
  const int i = blockIdx.x * 256 + threadIdx.x;
  if (i < n8) {
    const float4 a = in[2 * i], b = in[2 * i + 1];
    u32x4 o = { pack_bf16(a.x, a.y), pack_bf16(a.z, a.w),
                pack_bf16(b.x, b.y), pack_bf16(b.z, b.w) };
    out[i] = o;
  }
}

// ---------------- fused: sum split-K partials + bias + LayerNorm + exact GELU + l2norm
__global__ __launch_bounds__(256) void gee_fuse_ln1(
    const float* __restrict__ P, const float* __restrict__ b_enc,
    const float* __restrict__ g1, const float* __restrict__ b1,
    float* __restrict__ hx)
{
  const int row = blockIdx.x, tid = threadIdx.x;
  __shared__ float red[16];
  const size_t MN = (size_t)4096 * 512;
  float v[2];
#pragma unroll
  for (int e = 0; e < 2; ++e) {
    const int c = tid + e * 256;
    const size_t o = (size_t)row * 512 + c;
    v[e] = P[o] + P[MN + o] + P[2 * MN + o] + P[3 * MN + o] + b_enc[c];
  }
  float a = v[0] + v[1];
  float b = v[0] * v[0] + v[1] * v[1];
#pragma unroll
  for (int o = 32; o > 0; o >>= 1) { a += __shfl_xor(a, o); b += __shfl_xor(b, o); }
  const int lane = tid & 63, wvi = tid >> 6;
  if (lane == 0) { red[wvi] = a; red[8 + wvi] = b; }
  __syncthreads();
  const float mu  = (red[0] + red[1] + red[2] + red[3]) * (1.f / 512.f);
  const float ex2 = (red[8] + red[9] + red[10] + red[11]) * (1.f / 512.f);
  const float inv = rsqrtf(ex2 - mu * mu + 1e-5f);
  float gl[2], ss = 0.f;
#pragma unroll
  for (int e = 0; e < 2; ++e) {
    const int c = tid + e * 256;
    const float y = (v[e] - mu) * inv * g1[c] + b1[c];
    const float t = 0.5f * y * (1.f + erff(y * 0.70710678118654752f));
    gl[e] = t; ss += t * t;
  }
  __syncthreads();
#pragma unroll
  for (int o = 32; o > 0; o >>= 1) ss += __shfl_xor(ss, o);
  if (lane == 0) red[wvi] = ss;
  __syncthreads();
  const float nrm = sqrtf(red[0] + red[1] + red[2] + red[3]);
  const float sc = 1.f / fmaxf(nrm, 1e-12f);
#pragma unroll
  for (int e = 0; e < 2; ++e)
    hx[(size_t)row * 512 + tid + e * 256] = gl[e] * sc;
}

// ---------------- row l2norm of raw e [20000,512] fp32 -> eb bf16
__global__ __launch_bounds__(256) void gee_l2rows(
    const float* __restrict__ ein, ushort_t* __restrict__ eb)
{
  const int row = blockIdx.x, tid = threadIdx.x;
  __shared__ float red[4];
  const float2* er = (const float2*)(ein + (size_t)row * 512);
  const float2 v = er[tid];
  float ss = v.x * v.x + v.y * v.y;
#pragma unroll
  for (int o = 32; o > 0; o >>= 1) ss += __shfl_xor(ss, o);
  if ((tid & 63) == 0) red[tid >> 6] = ss;
  __syncthreads();
  const float sc = 1.f / fmaxf(sqrtf(red[0] + red[1] + red[2] + red[3]), 1e-12f);
  ((unsigned int*)eb)[(size_t)row * 256 + tid] = pack_bf16(v.x * sc, v.y * sc);
}

// ---------------- per-row top-64 via 4-nibble MSD radix select + softmax
__global__ __launch_bounds__(256) void gee_topk(
    const __half* __restrict__ scores, int* __restrict__ oidx, float* __restrict__ ow)
{
  const int row = blockIdx.x, tid = threadIdx.x;
  const int lane = tid & 63, wv = tid >> 6;
  constexpr int G = 20000;
  __shared__ ushort_t keys[G];
  __shared__ int whist[4][16];
  __shared__ int sel[64];
  __shared__ int tie[128];
  __shared__ int s_n1, s_n2, s_hi, s_above;

  // load + monotone map (pairs via u32)
  const unsigned int* srow32 = (const unsigned int*)((const ushort_t*)scores + (size_t)row * G);
  for (int j = tid; j < G / 2; j += 256) {
    const unsigned int p = srow32[j];
    unsigned int lo = p & 0xFFFFu, hi = p >> 16;
    lo = (lo & 0x8000u) ? (0xFFFFu & ~lo) : (lo | 0x8000u);
    hi = (hi & 0x8000u) ? (0xFFFFu & ~hi) : (hi | 0x8000u);
    ((unsigned int*)keys)[j] = lo | (hi << 16);
  }
  if (tid == 0) { s_hi = 0; s_above = 0; s_n1 = 0; s_n2 = 0; }
  __syncthreads();

  const int base = wv * 5000;
  for (int p = 0; p < 4; ++p) {
    const int shift = 12 - p * 4;
    const unsigned int maskHi = (p == 0) ? 0u : ((0xFFFFu << (shift + 4)) & 0xFFFFu);
    const unsigned int hiM = ((unsigned int)s_hi) & maskHi;
    int cnt[16];
#pragma unroll
    for (int b = 0; b < 16; ++b) cnt[b] = 0;
    for (int i0 = 0; i0 < 5000; i0 += 64) {
      const int ii = i0 + lane;
      const unsigned int k = keys[base + min(ii, 4999)];
      const bool act = (ii < 5000) && ((k & maskHi) == hiM);
      const unsigned int nib = (k >> shift) & 15u;
#pragma unroll
      for (int b = 0; b < 16; ++b) cnt[b] += (act && nib == (unsigned)b) ? 1 : 0;
    }
#pragma unroll
    for (int b = 0; b < 16; ++b) {
      int c = cnt[b];
#pragma unroll
      for (int o = 32; o > 0; o >>= 1) c += __shfl_xor(c, o);
      if (lane == 0) whist[wv][b] = c;
    }
    __syncthreads();
    if (tid == 0) {
      int run = s_above;
      for (int vv = 15; vv >= 0; --vv) {
        const int c = whist[0][vv] + whist[1][vv] + whist[2][vv] + whist[3][vv];
        if (run + c >= 64) { s_hi |= (vv << shift); s_above = run; break; }
        run += c;
      }
    }
    __syncthreads();
  }

  const int kthr = s_hi;
  for (int i = tid; i < G; i += 256) {
    const int k = keys[i];
    if (k > kthr) { const int pp = atomicAdd(&s_n1, 1); sel[pp] = i; }
    else if (k == kthr) { const int pp = atomicAdd(&s_n2, 1); if (pp < 128) tie[pp] = i; }
  }
  __syncthreads();
  if (tid == 0) {
    const int n1 = s_n1;
    const int n2 = min(s_n2, 128);
    const int need = 64 - n1;
    for (int rr = 0; rr < need; ++rr) {     // smallest indices (top_k tie-break)
      int best = 1 << 30, bj = 0;
      for (int j = 0; j < n2; ++j)
        if (tie[j] < best) { best = tie[j]; bj = j; }
      sel[n1 + rr] = best;
      tie[bj] = 1 << 30;
    }
  }
  __syncthreads();
  if (tid < 64) {
    const int idx = sel[tid];
    const float s = __half2float(scores[(size_t)row * G + idx]) * 10.0f;  // 1/T
    float m = s;
#pragma unroll
    for (int o = 32; o > 0; o >>= 1) m = fmaxf(m, __shfl_xor(m, o));
    const float w = __expf(s - m);
    float d = w;
#pragma unroll
    for (int o = 32; o > 0; o >>= 1) d += __shfl_xor(d, o);
    oidx[(size_t)row * 64 + tid] = idx;
    ow[(size_t)row * 64 + tid] = w / d;
  }
}

// ---------------- ctx[b] = sum_k attn_k * eb[idx_k]  (bf16 gather, fp32 accum)
__global__ __launch_bounds__(256) void gee_ctx(
    const int* __restrict__ idx, const float* __restrict__ w,
    const ushort_t* __restrict__ eb, float* __restrict__ ctx)
{
  const int row = blockIdx.x, tid = threadIdx.x;
  __shared__ int sidx[64];
  __shared__ float sw[64];
  if (tid < 64) { sidx[tid] = idx[(size_t)row * 64 + tid]; sw[tid] = w[(size_t)row * 64 + tid]; }
  __syncthreads();
  float a0 = 0.f, a1 = 0.f;
#pragma unroll 4
  for (int k = 0; k < 64; ++k) {
    const unsigned int pk = ((const unsigned int*)(eb + (size_t)sidx[k] * 512))[tid];
    const float wk = sw[k];
    a0 += wk * __uint_as_float(pk << 16);
    a1 += wk * __uint_as_float(pk & 0xFFFF0000u);
  }
  ((float2*)(ctx + (size_t)row * 512))[tid] = make_float2(a0, a1);
}

// ---------------- h_cell = (1+gamma)*h_x + beta
__global__ __launch_bounds__(256) void gee_film(
    const float4* __restrict__ gm, const float4* __restrict__ bt,
    const float4* __restrict__ hx, float4* __restrict__ hc, int n4)
{
  const int i = blockIdx.x * 256 + threadIdx.x;
  if (i < n4) {
    const float4 g = gm[i], b = bt[i], h = hx[i];
    float4 r;
    r.x = (1.f + g.x) * h.x + b.x;
    r.y = (1.f + g.y) * h.y + b.y;
    r.z = (1.f + g.z) * h.z + b.z;
    r.w = (1.f + g.w) * h.w + b.w;
    hc[i] = r;
  }
}

// ---------------- LN2 + exact GELU -> out [4096,1024]
__global__ __launch_bounds__(256) void gee_ln2(
    const float* __restrict__ h2, const float* __restrict__ g2,
    const float* __restrict__ b2, float* __restrict__ out)
{
  const int row = blockIdx.x, tid = threadIdx.x;
  __shared__ float red[16];
  float v[4];
  float a = 0.f, b = 0.f;
#pragma unroll
  for (int e = 0; e < 4; ++e) {
    v[e] = h2[(size_t)row * 1024 + tid + e * 256];
    a += v[e]; b += v[e] * v[e];
  }
#pragma unroll
  for (int o = 32; o > 0; o >>= 1) { a += __shfl_xor(a, o); b += __shfl_xor(b, o); }
  const int lane = tid & 63, wvi = tid >> 6;
  if (lane == 0) { red[wvi] = a; red[8 + wvi] = b; }
  __syncthreads();
  const float mu  = (red[0] + red[1] + red[2] + red[3]) * (1.f / 1024.f);
  const float ex2 = (red[8] + red[9] + red[10] + red[11]) * (1.f / 1024.f);
  const float inv = rsqrtf(ex2 - mu * mu + 1e-5f);
#pragma unroll
  for (int e = 0; e < 4; ++e) {
    const int c = tid + e * 256;
    const float y = (v[e] - mu) * inv * g2[c] + b2[c];
    out[(size_t)row * 1024 + c] = 0.5f * y * (1.f + erff(y * 0.70710678118654752f));
  }
}

extern "C" void kernel_launch(void* const* d_in, const int* in_sizes, int n_in,
                              void* d_out, int out_size, void* d_ws, size_t ws_size,
                              hipStream_t stream)
{
  const float* x       = (const float*)d_in[0];
  const float* g       = (const float*)d_in[1];
  const float* W_enc   = (const float*)d_in[2];
  const float* b_enc   = (const float*)d_in[3];
  const float* ln1_g   = (const float*)d_in[4];
  const float* ln1_b   = (const float*)d_in[5];
  const float* W_ga    = (const float*)d_in[6];
  const float* W_gamma = (const float*)d_in[7];
  const float* b_gamma = (const float*)d_in[8];
  const float* W_beta  = (const float*)d_in[9];
  const float* b_beta  = (const float*)d_in[10];
  const float* W_exp   = (const float*)d_in[11];
  const float* b_exp   = (const float*)d_in[12];
  const float* ln2_g   = (const float*)d_in[13];
  const float* ln2_b   = (const float*)d_in[14];
  float* out = (float*)d_out;

  char* ws = (char*)d_ws;
  // Region R1 (0..163.84MB) time-shared: part[1-2] -> scores[5-6] -> {ga,be,hc,h2}[8-11], ctx[7-8]@50.3MB
  constexpr size_t OFF_PART   = 0;            // 33,554,432
  constexpr size_t OFF_SCORES = 0;            // 163,840,000
  constexpr size_t OFF_GA     = 0;            // 8,388,608
  constexpr size_t OFF_BE     = 8388608;      // 8,388,608  (must be GA + M*N*4 for DUALB)
  constexpr size_t OFF_HC     = 16777216;     // 8,388,608
  constexpr size_t OFF_H2     = 25165824;     // 16,777,216
  constexpr size_t OFF_CTX    = 50331648;     // 8,388,608
  constexpr size_t OFF_WENCB  = 163840000;    // 20,480,000 (also eb later)
  constexpr size_t OFF_WGAB   = 184320000;    // 524,288
  constexpr size_t OFF_WGMB   = 184844288;    // 524,288
  constexpr size_t OFF_WBTB   = 185368576;    // 524,288
  constexpr size_t OFF_WEXB   = 185892864;    // 1,048,576
  constexpr size_t OFF_HX     = 186941440;    // 8,388,608
  constexpr size_t OFF_E      = 195330048;    // 40,960,000
  constexpr size_t OFF_TIDX   = 236290048;    // 1,048,576
  constexpr size_t OFF_TW     = 237338624;    // 1,048,576  -> total 238,387,200

  float*    part   = (float*)(ws + OFF_PART);
  __half*   scores = (__half*)(ws + OFF_SCORES);
  float*    ga     = (float*)(ws + OFF_GA);
  float*    be     = (float*)(ws + OFF_BE);
  float*    hc     = (float*)(ws + OFF_HC);
  float*    h2     = (float*)(ws + OFF_H2);
  float*    ctx    = (float*)(ws + OFF_CTX);
  ushort_t* wencb  = (ushort_t*)(ws + OFF_WENCB);
  ushort_t* eb     = (ushort_t*)(ws + OFF_WENCB);   // time-shared with wencb
  ushort_t* wgab   = (ushort_t*)(ws + OFF_WGAB);
  ushort_t* wgmb   = (ushort_t*)(ws + OFF_WGMB);
  ushort_t* wbtb   = (ushort_t*)(ws + OFF_WBTB);
  ushort_t* wexb   = (ushort_t*)(ws + OFF_WEXB);
  float*    hx     = (float*)(ws + OFF_HX);
  float*    e      = (float*)(ws + OFF_E);
  int*      tidx   = (int*)(ws + OFF_TIDX);
  float*    tw     = (float*)(ws + OFF_TW);

  // 0) weight converts fp32 -> bf16
  f2b<<<5000, 256, 0, stream>>>((const float4*)W_enc,   (u32x4*)wencb, 1280000);
  f2b<<<128,  256, 0, stream>>>((const float4*)W_ga,    (u32x4*)wgab,  32768);
  f2b<<<128,  256, 0, stream>>>((const float4*)W_gamma, (u32x4*)wgmb,  32768);
  f2b<<<128,  256, 0, stream>>>((const float4*)W_beta,  (u32x4*)wbtb,  32768);
  f2b<<<256,  256, 0, stream>>>((const float4*)W_exp,   (u32x4*)wexb,  65536);

  // 1) split-K=4 partials of x @ W_enc^T  -> part[4][4096][512]
  bgemm<4, false, false, float><<<512, 256, 0, stream>>>(
      x, wencb, nullptr, nullptr, nullptr, part, 4096, 512, 20000, 4, 32);
  // 2) h_x = l2norm(gelu(LN1(sum partials + b_enc)))
  gee_fuse_ln1<<<4096, 256, 0, stream>>>(part, b_enc, ln1_g, ln1_b, hx);
  // 3) e_raw = g @ W_ga^T  [20000][512]
  bgemm<1, false, false, float><<<628, 256, 0, stream>>>(
      g, wgab, nullptr, nullptr, nullptr, e, 20000, 512, 512, 4, 157);
  // 4) eb = l2norm rows (bf16)
  gee_l2rows<<<20000, 256, 0, stream>>>(e, eb);
  // 5) scores = h_x @ eb^T  (fp16 raw cosine; /T applied in topk)
  bgemm<1, false, false, __half><<<5024, 256, 0, stream>>>(
      hx, eb, nullptr, nullptr, nullptr, scores, 4096, 20000, 512, 157, 32);
  // 6) top-64 + softmax weights
  gee_topk<<<4096, 256, 0, stream>>>(scores, tidx, tw);
  // 7) ctx = attn-weighted sum of eb rows
  gee_ctx<<<4096, 256, 0, stream>>>(tidx, tw, eb, ctx);
  // 8) FiLM gamma (z=0) / beta (z=1) in one launch
  bgemm<1, true, true, float><<<256, 256, 0, stream>>>(
      ctx, wgmb, wbtb, b_gamma, b_beta, ga, 4096, 512, 512, 4, 32);
  // 9) h_cell = (1+gamma)*h_x + beta
  gee_film<<<2048, 256, 0, stream>>>((const float4*)ga, (const float4*)be,
                                     (const float4*)hx, (float4*)hc, 524288);
  // 10) h2 = h_cell @ W_exp^T + b_exp
  bgemm<1, false, true, float><<<256, 256, 0, stream>>>(
      hc, wexb, nullptr, b_exp, nullptr, h2, 4096, 1024, 512, 8, 32);
  // 11) out = gelu(LN2(h2))
  gee_ln2<<<4096, 256, 0, stream>>>(h2, ln2_g, ln2_b, out);
}

// Round 3
// 817.379 us; speedup vs baseline: 1.6973x; 1.4460x over previous
//
#include <hip/hip_runtime.h>
#include <hip/hip_fp16.h>
#include <math.h>
#include <type_traits>

#define DEVI __device__ __forceinline__

typedef __attribute__((ext_vector_type(8))) short bf16x8;
typedef __attribute__((ext_vector_type(4))) float f32x4;
typedef __attribute__((ext_vector_type(4))) unsigned int u32x4;
typedef unsigned short ushort_t;

DEVI unsigned int pack_bf16(float a, float b) {
  unsigned int ua = __float_as_uint(a), ub = __float_as_uint(b);
  ua = (ua + 0x7FFFu + ((ua >> 16) & 1u)) >> 16;   // RNE
  ub = (ub + 0x7FFFu + ((ub >> 16) & 1u)) >> 16;
  return ua | (ub << 16);
}

DEVI bf16x8 cvt_bf16x8(f32x4 lo, f32x4 hi) {
  unsigned int r0, r1, r2, r3;
  asm("v_cvt_pk_bf16_f32 %0, %1, %2" : "=v"(r0) : "v"(lo[0]), "v"(lo[1]));
  asm("v_cvt_pk_bf16_f32 %0, %1, %2" : "=v"(r1) : "v"(lo[2]), "v"(lo[3]));
  asm("v_cvt_pk_bf16_f32 %0, %1, %2" : "=v"(r2) : "v"(hi[0]), "v"(hi[1]));
  asm("v_cvt_pk_bf16_f32 %0, %1, %2" : "=v"(r3) : "v"(hi[2]), "v"(hi[3]));
  union { u32x4 u; bf16x8 v; } x;
  x.u = u32x4{r0, r1, r2, r3};
  return x.v;
}

// =======================================================================
// GEMM: C[M,N](+=bias) = A_fp32[M,K] * B_bf16[N,K]^T
// 128x128 tile, BK=64, 4 waves (64x64/wave).
// A staged fp32 via global_load_lds (32KB, swizzled byte^=(row&7)<<5),
// B staged bf16 via global_load_lds (16KB, swizzled byte^=(row&7)<<4).
// Swizzle: linear LDS dest + pre-swizzled GLOBAL source + swizzled ds_read.
// =======================================================================
template<int SPLITZ, bool DUALB, bool BIAS, typename OutT>
__global__ __launch_bounds__(256, 3) void bgemm(
    const float* __restrict__ A, const ushort_t* __restrict__ B0,
    const ushort_t* __restrict__ B1, const float* __restrict__ bias0,
    const float* __restrict__ bias1, OutT* __restrict__ C,
    int M, int N, int K, int nbn, int nbm)
{
  __shared__ __align__(16) float    As[32 * 256];   // 32 KB
  __shared__ __align__(16) ushort_t Bs[16 * 512];   // 16 KB
  const int tid = threadIdx.x, lane = tid & 63, wv = tid >> 6;

  // bijective XCD remap of flat block id (m204)
  const int nwg = gridDim.x;
  const int hw = blockIdx.x;
  const int q = nwg >> 3, r = nwg & 7;
  const int xcd = hw & 7, pos = hw >> 3;
  const int lid = (xcd < r ? xcd * (q + 1) : r * (q + 1) + (xcd - r) * q) + pos;
  const int bn = lid % nbn;
  const int t2 = lid / nbn;
  const int bm = t2 % nbm;
  const int z  = t2 / nbm;

  const ushort_t* B  = (DUALB && z == 1) ? B1 : B0;
  const float* bias  = (DUALB && z == 1) ? bias1 : bias0;

  const int ksteps = (K + 63) >> 6;
  int kbBeg = 0, kbEnd = ksteps;
  if (SPLITZ > 1) {
    const int sz = (ksteps + SPLITZ - 1) / SPLITZ;
    kbBeg = z * sz;
    kbEnd = min(ksteps, kbBeg + sz);
  }

  const int wr = (wv >> 1) * 64, wc = (wv & 1) * 64;
  const int lrow = lane & 15, kg = lane >> 4;

  f32x4 acc[4][4];
#pragma unroll
  for (int i = 0; i < 4; ++i)
#pragma unroll
    for (int j = 0; j < 4; ++j) acc[i][j] = f32x4{0.f, 0.f, 0.f, 0.f};

  // staging addressing (pre-swizzled source columns)
  const int rA0  = wv * 4 + (lane >> 4);                                  // + j*16
  const int colA = (((lane & 15) << 4) ^ ((rA0 & 7) << 5)) >> 2;          // float idx in [0,64)
  const int rB0  = wv * 8 + (lane >> 3);                                  // + j*32
  const int colB = (((lane & 7) << 4) ^ ((rB0 & 7) << 4)) >> 1;           // bf16 idx in [0,64)

  const float* aSrc[8];
#pragma unroll
  for (int j = 0; j < 8; ++j) {
    const int grow = min(bm * 128 + rA0 + j * 16, M - 1);
    aSrc[j] = A + (size_t)grow * (size_t)K + colA;
  }
  const ushort_t* bSrc[4];
#pragma unroll
  for (int j = 0; j < 4; ++j) {
    const int grow = min(bn * 128 + rB0 + j * 32, N - 1);
    bSrc[j] = B + (size_t)grow * (size_t)K + colB;
  }

  for (int kb = kbBeg; kb < kbEnd; ++kb) {
    const int k0 = kb << 6;
    if (k0 + 64 <= K) {
#pragma unroll
      for (int j = 0; j < 8; ++j)
        __builtin_amdgcn_global_load_lds(
            (const __attribute__((address_space(1))) void*)(aSrc[j] + k0),
            (__attribute__((address_space(3))) void*)&As[(j * 4 + wv) * 256], 16, 0, 0);
#pragma unroll
      for (int j = 0; j < 4; ++j)
        __builtin_amdgcn_global_load_lds(
            (const __attribute__((address_space(1))) void*)(bSrc[j] + k0),
            (__attribute__((address_space(3))) void*)&Bs[(j * 4 + wv) * 512], 16, 0, 0);
    } else {
#pragma unroll
      for (int j = 0; j < 8; ++j) {
        float4 f = make_float4(0.f, 0.f, 0.f, 0.f);
        if (k0 + colA + 4 <= K) f = *(const float4*)(aSrc[j] + k0);
        *(float4*)((char*)As + (j * 4 + wv) * 1024 + lane * 16) = f;
      }
#pragma unroll
      for (int j = 0; j < 4; ++j) {
        u32x4 v = {0u, 0u, 0u, 0u};
        if (k0 + colB + 8 <= K) v = *(const u32x4*)(bSrc[j] + k0);
        *(u32x4*)((char*)Bs + (j * 4 + wv) * 1024 + lane * 16) = v;
      }
    }
    __syncthreads();
#pragma unroll
    for (int kk = 0; kk < 2; ++kk) {
      bf16x8 af[4], bfr[4];
#pragma unroll
      for (int i = 0; i < 4; ++i) {
        const int ra = wr + i * 16 + lrow;
        const int ab = (kk * 128 + (kg << 5)) ^ ((ra & 7) << 5);
        const char* pa = (const char*)As + ra * 256 + ab;
        af[i] = cvt_bf16x8(*(const f32x4*)pa, *(const f32x4*)(pa + 16));
        const int rb = wc + i * 16 + lrow;
        const int bb = (kk * 64 + (kg << 4)) ^ ((rb & 7) << 4);
        bfr[i] = *(const bf16x8*)((const char*)Bs + rb * 128 + bb);
      }
#pragma unroll
      for (int i = 0; i < 4; ++i)
#pragma unroll
        for (int j = 0; j < 4; ++j)
          acc[i][j] = __builtin_amdgcn_mfma_f32_16x16x32_bf16(af[i], bfr[j], acc[i][j], 0, 0, 0);
    }
    __syncthreads();
  }

  const size_t zoff = (SPLITZ > 1 || DUALB) ? (size_t)z * (size_t)M * (size_t)N : 0;
#pragma unroll
  for (int i = 0; i < 4; ++i) {
#pragma unroll
    for (int j = 0; j < 4; ++j) {
      const int col = bn * 128 + wc + j * 16 + lrow;
      if (col >= N) continue;
      const int row0 = bm * 128 + wr + i * 16 + kg * 4;
      float bv = 0.f;
      if (BIAS) bv = bias[col];
#pragma unroll
      for (int rr = 0; rr < 4; ++rr) {
        const int gr = row0 + rr;
        if (gr < M) {
          const float v = acc[i][j][rr] + bv;
          if constexpr (std::is_same<OutT, __half>::value)
            C[zoff + (size_t)gr * (size_t)N + col] = __float2half(v);
          else
            C[zoff + (size_t)gr * (size_t)N + col] = v;
        }
      }
    }
  }
}

// ---------------- fp32 -> bf16 convert (8 elems/thread)
__global__ __launch_bounds__(256) void f2b(
    const float4* __restrict__ in, u32x4* __restrict__ out, int n8)
{
  const int i = blockIdx.x * 256 + threadIdx.x;
  if (i < n8) {
    const float4 a = in[2 * i], b = in[2 * i + 1];
    u32x4 o = { pack_bf16(a.x, a.y), pack_bf16(a.z, a.w),
                pack_bf16(b.x, b.y), pack_bf16(b.z, b.w) };
    out[i] = o;
  }
}

// ---------------- fused: sum split-K partials + bias + LayerNorm + exact GELU + l2norm
__global__ __launch_bounds__(256) void gee_fuse_ln1(
    const float* __restrict__ P, const float* __restrict__ b_enc,
    const float* __restrict__ g1, const float* __restrict__ b1,
    float* __restrict__ hx)
{
  const int row = blockIdx.x, tid = threadIdx.x;
  __shared__ float red[16];
  const size_t MN = (size_t)4096 * 512;
  float v[2];
#pragma unroll
  for (int e = 0; e < 2; ++e) {
    const int c = tid + e * 256;
    const size_t o = (size_t)row * 512 + c;
    v[e] = P[o] + P[MN + o] + P[2 * MN + o] + P[3 * MN + o] + b_enc[c];
  }
  float a = v[0] + v[1];
  float b = v[0] * v[0] + v[1] * v[1];
#pragma unroll
  for (int o = 32; o > 0; o >>= 1) { a += __shfl_xor(a, o); b += __shfl_xor(b, o); }
  const int lane = tid & 63, wvi = tid >> 6;
  if (lane == 0) { red[wvi] = a; red[8 + wvi] = b; }
  __syncthreads();
  const float mu  = (red[0] + red[1] + red[2] + red[3]) * (1.f / 512.f);
  const float ex2 = (red[8] + red[9] + red[10] + red[11]) * (1.f / 512.f);
  const float inv = rsqrtf(ex2 - mu * mu + 1e-5f);
  float gl[2], ss = 0.f;
#pragma unroll
  for (int e = 0; e < 2; ++e) {
    const int c = tid + e * 256;
    const float y = (v[e] - mu) * inv * g1[c] + b1[c];
    const float t = 0.5f * y * (1.f + erff(y * 0.70710678118654752f));
    gl[e] = t; ss += t * t;
  }
  __syncthreads();
#pragma unroll
  for (int o = 32; o > 0; o >>= 1) ss += __shfl_xor(ss, o);
  if (lane == 0) red[wvi] = ss;
  __syncthreads();
  const float nrm = sqrtf(red[0] + red[1] + red[2] + red[3]);
  const float sc = 1.f / fmaxf(nrm, 1e-12f);
#pragma unroll
  for (int e = 0; e < 2; ++e)
    hx[(size_t)row * 512 + tid + e * 256] = gl[e] * sc;
}

// ---------------- row l2norm of raw e [20000,512] fp32 -> eb bf16
__global__ __launch_bounds__(256) void gee_l2rows(
    const float* __restrict__ ein, ushort_t* __restrict__ eb)
{
  const int row = blockIdx.x, tid = threadIdx.x;
  __shared__ float red[4];
  const float2* er = (const float2*)(ein + (size_t)row * 512);
  const float2 v = er[tid];
  float ss = v.x * v.x + v.y * v.y;
#pragma unroll
  for (int o = 32; o > 0; o >>= 1) ss += __shfl_xor(ss, o);
  if ((tid & 63) == 0) red[tid >> 6] = ss;
  __syncthreads();
  const float sc = 1.f / fmaxf(sqrtf(red[0] + red[1] + red[2] + red[3]), 1e-12f);
  ((unsigned int*)eb)[(size_t)row * 256 + tid] = pack_bf16(v.x * sc, v.y * sc);
}

// ---------------- per-row top-64: ballot-counted radix select + compaction
__global__ __launch_bounds__(256) void gee_topk(
    const __half* __restrict__ scores, int* __restrict__ oidx, float* __restrict__ ow)
{
  constexpr int G = 20000, GP = G / 2, CAP = 2048, TCAP = 160;
  const int row = blockIdx.x, tid = threadIdx.x;
  const int lane = tid & 63, wv = tid >> 6;
  __shared__ unsigned int comp[CAP];   // (key<<16) | idx
  __shared__ int whist[4][16];
  __shared__ int sel[64];
  __shared__ int tie[TCAP];
  __shared__ int s_thr, s_above, s_cand, s_cnt, s_n1, s_n2;

  const unsigned int* srow32 =
      (const unsigned int*)((const ushort_t*)scores + (size_t)row * G);
  const ushort_t* srow16 = (const ushort_t*)srow32;

  if (tid == 0) { s_thr = 0; s_above = 0; s_cand = 0; s_cnt = 0; s_n1 = 0; s_n2 = 0; }
  __syncthreads();

  // ---- passes 0,1: pair-wise global scans, 16-bin ballot histograms
  for (int pass = 0; pass < 2; ++pass) {
    const int shift = 12 - 4 * pass;
    const unsigned int thr = (unsigned int)s_thr;
    const unsigned int pfx = thr >> (shift + 4);
    int c[16];
#pragma unroll
    for (int b = 0; b < 16; ++b) c[b] = 0;
    for (int j0 = 0; j0 < GP; j0 += 256) {
      const int j = j0 + tid;
      const bool ok = j < GP;
      const unsigned int p = ok ? srow32[j] : 0u;
      unsigned int lo = p & 0xFFFFu, hi = p >> 16;
      lo = (lo & 0x8000u) ? (0xFFFFu & ~lo) : (lo | 0x8000u);
      hi = (hi & 0x8000u) ? (0xFFFFu & ~hi) : (hi | 0x8000u);
      const unsigned int nl = (ok && (lo >> (shift + 4)) == pfx) ? ((lo >> shift) & 15u) : 0xFFu;
      const unsigned int nh = (ok && (hi >> (shift + 4)) == pfx) ? ((hi >> shift) & 15u) : 0xFFu;
#pragma unroll
      for (int b = 0; b < 16; ++b) {
        c[b] += __popcll(__ballot(nl == (unsigned)b));
        c[b] += __popcll(__ballot(nh == (unsigned)b));
      }
    }
    if (lane == 0) {
#pragma unroll
      for (int b = 0; b < 16; ++b) whist[wv][b] = c[b];
    }
    __syncthreads();
    if (tid == 0) {
      int run = s_above;
      for (int vv = 15; vv >= 0; --vv) {
        const int c4 = whist[0][vv] + whist[1][vv] + whist[2][vv] + whist[3][vv];
        if (run + c4 >= 64) { s_thr |= vv << shift; s_cand = run + c4; break; }
        run += c4;
      }
      s_above = run;
    }
    __syncthreads();
  }

  const bool useComp = (s_cand <= CAP);
  const unsigned int thrB = ((unsigned int)s_thr) >> 8;   // byte prefix

  // ---- compaction: keep (key>>8) >= thrB  (exactly s_cand elements)
  if (useComp) {
    for (int j0 = 0; j0 < GP; j0 += 256) {
      const int j = j0 + tid;
      if (j < GP) {
        const unsigned int p = srow32[j];
        unsigned int lo = p & 0xFFFFu, hi = p >> 16;
        lo = (lo & 0x8000u) ? (0xFFFFu & ~lo) : (lo | 0x8000u);
        hi = (hi & 0x8000u) ? (0xFFFFu & ~hi) : (hi | 0x8000u);
        if ((lo >> 8) >= thrB) {
          const int pos = atomicAdd(&s_cnt, 1);
          comp[pos] = (lo << 16) | (unsigned)(2 * j);
        }
        if ((hi >> 8) >= thrB) {
          const int pos = atomicAdd(&s_cnt, 1);
          comp[pos] = (hi << 16) | (unsigned)(2 * j + 1);
        }
      }
    }
  }
  __syncthreads();
  const int Nloop = useComp ? s_cnt : G;

  // ---- passes 2,3: element-wise over compact list (or global fallback)
  for (int pass = 2; pass < 4; ++pass) {
    const int shift = 12 - 4 * pass;
    const unsigned int thr = (unsigned int)s_thr;
    const unsigned int pfx = thr >> (shift + 4);
    int c[16];
#pragma unroll
    for (int b = 0; b < 16; ++b) c[b] = 0;
    for (int j0 = 0; j0 < Nloop; j0 += 256) {
      const int j = j0 + tid;
      const bool ok = j < Nloop;
      unsigned int key;
      if (useComp) {
        key = ok ? (comp[j] >> 16) : 0u;
      } else {
        const unsigned int raw = ok ? (unsigned int)srow16[j] : 0u;
        key = (raw & 0x8000u) ? (0xFFFFu & ~raw) : (raw | 0x8000u);
      }
      const unsigned int nb = (ok && (key >> (shift + 4)) == pfx) ? ((key >> shift) & 15u) : 0xFFu;
#pragma unroll
      for (int b = 0; b < 16; ++b) c[b] += __popcll(__ballot(nb == (unsigned)b));
    }
    if (lane == 0) {
#pragma unroll
      for (int b = 0; b < 16; ++b) whist[wv][b] = c[b];
    }
    __syncthreads();
    if (tid == 0) {
      int run = s_above;
      for (int vv = 15; vv >= 0; --vv) {
        const int c4 = whist[0][vv] + whist[1][vv] + whist[2][vv] + whist[3][vv];
        if (run + c4 >= 64) { s_thr |= vv << shift; break; }
        run += c4;
      }
      s_above = run;
    }
    __syncthreads();
  }

  // ---- selection: key > kthr -> sel, == kthr -> tie
  const unsigned int kthr = (unsigned int)s_thr;
  for (int j0 = 0; j0 < Nloop; j0 += 256) {
    const int j = j0 + tid;
    if (j < Nloop) {
      unsigned int key, idx;
      if (useComp) {
        const unsigned int u = comp[j];
        key = u >> 16; idx = u & 0xFFFFu;
      } else {
        const unsigned int raw = (unsigned int)srow16[j];
        key = (raw & 0x8000u) ? (0xFFFFu & ~raw) : (raw | 0x8000u);
        idx = (unsigned)j;
      }
      if (key > kthr) {
        const int pos = atomicAdd(&s_n1, 1);
        sel[pos] = (int)idx;
      } else if (key == kthr) {
        const int pos = atomicAdd(&s_n2, 1);
        if (pos < TCAP) tie[pos] = (int)idx;
      }
    }
  }
  __syncthreads();
  if (tid == 0) {
    const int n1 = s_n1;
    const int n2 = min(s_n2, TCAP);
    const int need = 64 - n1;
    for (int rr = 0; rr < need; ++rr) {     // smallest indices (top_k tie-break)
      int best = 1 << 30, bj = 0;
      for (int j = 0; j < n2; ++j)
        if (tie[j] < best) { best = tie[j]; bj = j; }
      sel[n1 + rr] = best;
      tie[bj] = 1 << 30;
    }
  }
  __syncthreads();
  if (tid < 64) {
    const int idx = sel[tid];
    const float s = __half2float(scores[(size_t)row * G + idx]) * 10.0f;  // 1/T
    float m = s;
#pragma unroll
    for (int o = 32; o > 0; o >>= 1) m = fmaxf(m, __shfl_xor(m, o));
    const float w = __expf(s - m);
    float d = w;
#pragma unroll
    for (int o = 32; o > 0; o >>= 1) d += __shfl_xor(d, o);
    oidx[(size_t)row * 64 + tid] = idx;
    ow[(size_t)row * 64 + tid] = w / d;
  }
}

// ---------------- ctx[b] = sum_k attn_k * eb[idx_k]  (bf16 gather, fp32 accum)
__global__ __launch_bounds__(256) void gee_ctx(
    const int* __restrict__ idx, const float* __restrict__ w,
    const ushort_t* __restrict__ eb, float* __restrict__ ctx)
{
  const int row = blockIdx.x, tid = threadIdx.x;
  __shared__ int sidx[64];
  __shared__ float sw[64];
  if (tid < 64) { sidx[tid] = idx[(size_t)row * 64 + tid]; sw[tid] = w[(size_t)row * 64 + tid]; }
  __syncthreads();
  float a0 = 0.f, a1 = 0.f;
#pragma unroll 4
  for (int k = 0; k < 64; ++k) {
    const unsigned int pk = ((const unsigned int*)(eb + (size_t)sidx[k] * 512))[tid];
    const float wk = sw[k];
    a0 += wk * __uint_as_float(pk << 16);
    a1 += wk * __uint_as_float(pk & 0xFFFF0000u);
  }
  ((float2*)(ctx + (size_t)row * 512))[tid] = make_float2(a0, a1);
}

// ---------------- h_cell = (1+gamma)*h_x + beta
__global__ __launch_bounds__(256) void gee_film(
    const float4* __restrict__ gm, const float4* __restrict__ bt,
    const float4* __restrict__ hx, float4* __restrict__ hc, int n4)
{
  const int i = blockIdx.x * 256 + threadIdx.x;
  if (i < n4) {
    const float4 g = gm[i], b = bt[i], h = hx[i];
    float4 r;
    r.x = (1.f + g.x) * h.x + b.x;
    r.y = (1.f + g.y) * h.y + b.y;
    r.z = (1.f + g.z) * h.z + b.z;
    r.w = (1.f + g.w) * h.w + b.w;
    hc[i] = r;
  }
}

// ---------------- LN2 + exact GELU -> out [4096,1024]
__global__ __launch_bounds__(256) void gee_ln2(
    const float* __restrict__ h2, const float* __restrict__ g2,
    const float* __restrict__ b2, float* __restrict__ out)
{
  const int row = blockIdx.x, tid = threadIdx.x;
  __shared__ float red[16];
  float v[4];
  float a = 0.f, b = 0.f;
#pragma unroll
  for (int e = 0; e < 4; ++e) {
    v[e] = h2[(size_t)row * 1024 + tid + e * 256];
    a += v[e]; b += v[e] * v[e];
  }
#pragma unroll
  for (int o = 32; o > 0; o >>= 1) { a += __shfl_xor(a, o); b += __shfl_xor(b, o); }
  const int lane = tid & 63, wvi = tid >> 6;
  if (lane == 0) { red[wvi] = a; red[8 + wvi] = b; }
  __syncthreads();
  const float mu  = (red[0] + red[1] + red[2] + red[3]) * (1.f / 1024.f);
  const float ex2 = (red[8] + red[9] + red[10] + red[11]) * (1.f / 1024.f);
  const float inv = rsqrtf(ex2 - mu * mu + 1e-5f);
#pragma unroll
  for (int e = 0; e < 4; ++e) {
    const int c = tid + e * 256;
    const float y = (v[e] - mu) * inv * g2[c] + b2[c];
    out[(size_t)row * 1024 + c] = 0.5f * y * (1.f + erff(y * 0.70710678118654752f));
  }
}

extern "C" void kernel_launch(void* const* d_in, const int* in_sizes, int n_in,
                              void* d_out, int out_size, void* d_ws, size_t ws_size,
                              hipStream_t stream)
{
  const float* x       = (const float*)d_in[0];
  const float* g       = (const float*)d_in[1];
  const float* W_enc   = (const float*)d_in[2];
  const float* b_enc   = (const float*)d_in[3];
  const float* ln1_g   = (const float*)d_in[4];
  const float* ln1_b   = (const float*)d_in[5];
  const float* W_ga    = (const float*)d_in[6];
  const float* W_gamma = (const float*)d_in[7];
  const float* b_gamma = (const float*)d_in[8];
  const float* W_beta  = (const float*)d_in[9];
  const float* b_beta  = (const float*)d_in[10];
  const float* W_exp   = (const float*)d_in[11];
  const float* b_exp   = (const float*)d_in[12];
  const float* ln2_g   = (const float*)d_in[13];
  const float* ln2_b   = (const float*)d_in[14];
  float* out = (float*)d_out;

  char* ws = (char*)d_ws;
  constexpr size_t OFF_PART   = 0;            // 33,554,432
  constexpr size_t OFF_SCORES = 0;            // 163,840,000
  constexpr size_t OFF_GA     = 0;            // 8,388,608
  constexpr size_t OFF_BE     = 8388608;      // 8,388,608  (GA + M*N*4 for DUALB)
  constexpr size_t OFF_HC     = 16777216;     // 8,388,608
  constexpr size_t OFF_H2     = 25165824;     // 16,777,216
  constexpr size_t OFF_CTX    = 50331648;     // 8,388,608
  constexpr size_t OFF_WENCB  = 163840000;    // 20,480,000 (also eb later)
  constexpr size_t OFF_WGAB   = 184320000;    // 524,288
  constexpr size_t OFF_WGMB   = 184844288;    // 524,288
  constexpr size_t OFF_WBTB   = 185368576;    // 524,288
  constexpr size_t OFF_WEXB   = 185892864;    // 1,048,576
  constexpr size_t OFF_HX     = 186941440;    // 8,388,608
  constexpr size_t OFF_E      = 195330048;    // 40,960,000
  constexpr size_t OFF_TIDX   = 236290048;    // 1,048,576
  constexpr size_t OFF_TW     = 237338624;    // 1,048,576  -> total 238,387,200

  float*    part   = (float*)(ws + OFF_PART);
  __half*   scores = (__half*)(ws + OFF_SCORES);
  float*    ga     = (float*)(ws + OFF_GA);
  float*    be     = (float*)(ws + OFF_BE);
  float*    hc     = (float*)(ws + OFF_HC);
  float*    h2     = (float*)(ws + OFF_H2);
  float*    ctx    = (float*)(ws + OFF_CTX);
  ushort_t* wencb  = (ushort_t*)(ws + OFF_WENCB);
  ushort_t* eb     = (ushort_t*)(ws + OFF_WENCB);   // time-shared with wencb
  ushort_t* wgab   = (ushort_t*)(ws + OFF_WGAB);
  ushort_t* wgmb   = (ushort_t*)(ws + OFF_WGMB);
  ushort_t* wbtb   = (ushort_t*)(ws + OFF_WBTB);
  ushort_t* wexb   = (ushort_t*)(ws + OFF_WEXB);
  float*    hx     = (float*)(ws + OFF_HX);
  float*    e      = (float*)(ws + OFF_E);
  int*      tidx   = (int*)(ws + OFF_TIDX);
  float*    tw     = (float*)(ws + OFF_TW);

  // 0) weight converts fp32 -> bf16
  f2b<<<5000, 256, 0, stream>>>((const float4*)W_enc,   (u32x4*)wencb, 1280000);
  f2b<<<128,  256, 0, stream>>>((const float4*)W_ga,    (u32x4*)wgab,  32768);
  f2b<<<128,  256, 0, stream>>>((const float4*)W_gamma, (u32x4*)wgmb,  32768);
  f2b<<<128,  256, 0, stream>>>((const float4*)W_beta,  (u32x4*)wbtb,  32768);
  f2b<<<256,  256, 0, stream>>>((const float4*)W_exp,   (u32x4*)wexb,  65536);

  // 1) split-K=4 partials of x @ W_enc^T  -> part[4][4096][512]
  bgemm<4, false, false, float><<<512, 256, 0, stream>>>(
      x, wencb, nullptr, nullptr, nullptr, part, 4096, 512, 20000, 4, 32);
  // 2) h_x = l2norm(gelu(LN1(sum partials + b_enc)))
  gee_fuse_ln1<<<4096, 256, 0, stream>>>(part, b_enc, ln1_g, ln1_b, hx);
  // 3) e_raw = g @ W_ga^T  [20000][512]
  bgemm<1, false, false, float><<<628, 256, 0, stream>>>(
      g, wgab, nullptr, nullptr, nullptr, e, 20000, 512, 512, 4, 157);
  // 4) eb = l2norm rows (bf16)
  gee_l2rows<<<20000, 256, 0, stream>>>(e, eb);
  // 5) scores = h_x @ eb^T  (fp16 raw cosine; /T applied in topk)
  bgemm<1, false, false, __half><<<5024, 256, 0, stream>>>(
      hx, eb, nullptr, nullptr, nullptr, scores, 4096, 20000, 512, 157, 32);
  // 6) top-64 + softmax weights
  gee_topk<<<4096, 256, 0, stream>>>(scores, tidx, tw);
  // 7) ctx = attn-weighted sum of eb rows
  gee_ctx<<<4096, 256, 0, stream>>>(tidx, tw, eb, ctx);
  // 8) FiLM gamma (z=0) / beta (z=1) in one launch
  bgemm<1, true, true, float><<<256, 256, 0, stream>>>(
      ctx, wgmb, wbtb, b_gamma, b_beta, ga, 4096, 512, 512, 4, 32);
  // 9) h_cell = (1+gamma)*h_x + beta
  gee_film<<<2048, 256, 0, stream>>>((const float4*)ga, (const float4*)be,
                                     (const float4*)hx, (float4*)hc, 524288);
  // 10) h2 = h_cell @ W_exp^T + b_exp
  bgemm<1, false, true, float><<<256, 256, 0, stream>>>(
      hc, wexb, nullptr, b_exp, nullptr, h2, 4096, 1024, 512, 8, 32);
  // 11) out = gelu(LN2(h2))
  gee_ln2<<<4096, 256, 0, stream>>>(h2, ln2_g, ln2_b, out);
}

// Round 4
// 561.553 us; speedup vs baseline: 2.4705x; 1.4556x over previous
//
#include <hip/hip_runtime.h>
#include <hip/hip_fp16.h>
#include <math.h>
#include <type_traits>

#define DEVI __device__ __forceinline__

typedef __attribute__((ext_vector_type(8))) short bf16x8;
typedef __attribute__((ext_vector_type(4))) float f32x4;
typedef __attribute__((ext_vector_type(4))) unsigned int u32x4;
typedef unsigned short ushort_t;

DEVI unsigned int pack_bf16(float a, float b) {
  unsigned int ua = __float_as_uint(a), ub = __float_as_uint(b);
  ua = (ua + 0x7FFFu + ((ua >> 16) & 1u)) >> 16;   // RNE
  ub = (ub + 0x7FFFu + ((ub >> 16) & 1u)) >> 16;
  return ua | (ub << 16);
}

DEVI bf16x8 cvt_bf16x8(f32x4 lo, f32x4 hi) {
  unsigned int r0, r1, r2, r3;
  asm("v_cvt_pk_bf16_f32 %0, %1, %2" : "=v"(r0) : "v"(lo[0]), "v"(lo[1]));
  asm("v_cvt_pk_bf16_f32 %0, %1, %2" : "=v"(r1) : "v"(lo[2]), "v"(lo[3]));
  asm("v_cvt_pk_bf16_f32 %0, %1, %2" : "=v"(r2) : "v"(hi[0]), "v"(hi[1]));
  asm("v_cvt_pk_bf16_f32 %0, %1, %2" : "=v"(r3) : "v"(hi[2]), "v"(hi[3]));
  union { u32x4 u; bf16x8 v; } x;
  x.u = u32x4{r0, r1, r2, r3};
  return x.v;
}

// =======================================================================
// GEMM: C[M,N](+=bias) = A_fp32[M,K] * B_bf16[N,K]^T
// 128x128 tile, BK=64, 4 waves (64x64/wave).
// A staged fp32 via global_load_lds (32KB, swizzled byte^=(row&7)<<5),
// B staged bf16 via global_load_lds (16KB, swizzled byte^=(row&7)<<4).
// Swizzle: linear LDS dest + pre-swizzled GLOBAL source + swizzled ds_read.
// =======================================================================
template<int SPLITZ, bool DUALB, bool BIAS, typename OutT>
__global__ __launch_bounds__(256, 3) void bgemm(
    const float* __restrict__ A, const ushort_t* __restrict__ B0,
    const ushort_t* __restrict__ B1, const float* __restrict__ bias0,
    const float* __restrict__ bias1, OutT* __restrict__ C,
    int M, int N, int K, int nbn, int nbm)
{
  __shared__ __align__(16) float    As[32 * 256];   // 32 KB
  __shared__ __align__(16) ushort_t Bs[16 * 512];   // 16 KB
  const int tid = threadIdx.x, lane = tid & 63, wv = tid >> 6;

  // bijective XCD remap of flat block id (m204)
  const int nwg = gridDim.x;
  const int hw = blockIdx.x;
  const int q = nwg >> 3, r = nwg & 7;
  const int xcd = hw & 7, pos = hw >> 3;
  const int lid = (xcd < r ? xcd * (q + 1) : r * (q + 1) + (xcd - r) * q) + pos;
  const int bn = lid % nbn;
  const int t2 = lid / nbn;
  const int bm = t2 % nbm;
  const int z  = t2 / nbm;

  const ushort_t* B  = (DUALB && z == 1) ? B1 : B0;
  const float* bias  = (DUALB && z == 1) ? bias1 : bias0;

  const int ksteps = (K + 63) >> 6;
  int kbBeg = 0, kbEnd = ksteps;
  if (SPLITZ > 1) {
    const int sz = (ksteps + SPLITZ - 1) / SPLITZ;
    kbBeg = z * sz;
    kbEnd = min(ksteps, kbBeg + sz);
  }

  const int wr = (wv >> 1) * 64, wc = (wv & 1) * 64;
  const int lrow = lane & 15, kg = lane >> 4;

  f32x4 acc[4][4];
#pragma unroll
  for (int i = 0; i < 4; ++i)
#pragma unroll
    for (int j = 0; j < 4; ++j) acc[i][j] = f32x4{0.f, 0.f, 0.f, 0.f};

  // staging addressing (pre-swizzled source columns)
  const int rA0  = wv * 4 + (lane >> 4);                                  // + j*16
  const int colA = (((lane & 15) << 4) ^ ((rA0 & 7) << 5)) >> 2;          // float idx in [0,64)
  const int rB0  = wv * 8 + (lane >> 3);                                  // + j*32
  const int colB = (((lane & 7) << 4) ^ ((rB0 & 7) << 4)) >> 1;           // bf16 idx in [0,64)

  const float* aSrc[8];
#pragma unroll
  for (int j = 0; j < 8; ++j) {
    const int grow = min(bm * 128 + rA0 + j * 16, M - 1);
    aSrc[j] = A + (size_t)grow * (size_t)K + colA;
  }
  const ushort_t* bSrc[4];
#pragma unroll
  for (int j = 0; j < 4; ++j) {
    const int grow = min(bn * 128 + rB0 + j * 32, N - 1);
    bSrc[j] = B + (size_t)grow * (size_t)K + colB;
  }

  for (int kb = kbBeg; kb < kbEnd; ++kb) {
    const int k0 = kb << 6;
    if (k0 + 64 <= K) {
#pragma unroll
      for (int j = 0; j < 8; ++j)
        __builtin_amdgcn_global_load_lds(
            (const __attribute__((address_space(1))) void*)(aSrc[j] + k0),
            (__attribute__((address_space(3))) void*)&As[(j * 4 + wv) * 256], 16, 0, 0);
#pragma unroll
      for (int j = 0; j < 4; ++j)
        __builtin_amdgcn_global_load_lds(
            (const __attribute__((address_space(1))) void*)(bSrc[j] + k0),
            (__attribute__((address_space(3))) void*)&Bs[(j * 4 + wv) * 512], 16, 0, 0);
    } else {
#pragma unroll
      for (int j = 0; j < 8; ++j) {
        float4 f = make_float4(0.f, 0.f, 0.f, 0.f);
        if (k0 + colA + 4 <= K) f = *(const float4*)(aSrc[j] + k0);
        *(float4*)((char*)As + (j * 4 + wv) * 1024 + lane * 16) = f;
      }
#pragma unroll
      for (int j = 0; j < 4; ++j) {
        u32x4 v = {0u, 0u, 0u, 0u};
        if (k0 + colB + 8 <= K) v = *(const u32x4*)(bSrc[j] + k0);
        *(u32x4*)((char*)Bs + (j * 4 + wv) * 1024 + lane * 16) = v;
      }
    }
    __syncthreads();
#pragma unroll
    for (int kk = 0; kk < 2; ++kk) {
      bf16x8 af[4], bfr[4];
#pragma unroll
      for (int i = 0; i < 4; ++i) {
        const int ra = wr + i * 16 + lrow;
        const int ab = (kk * 128 + (kg << 5)) ^ ((ra & 7) << 5);
        const char* pa = (const char*)As + ra * 256 + ab;
        af[i] = cvt_bf16x8(*(const f32x4*)pa, *(const f32x4*)(pa + 16));
        const int rb = wc + i * 16 + lrow;
        const int bb = (kk * 64 + (kg << 4)) ^ ((rb & 7) << 4);
        bfr[i] = *(const bf16x8*)((const char*)Bs + rb * 128 + bb);
      }
#pragma unroll
      for (int i = 0; i < 4; ++i)
#pragma unroll
        for (int j = 0; j < 4; ++j)
          acc[i][j] = __builtin_amdgcn_mfma_f32_16x16x32_bf16(af[i], bfr[j], acc[i][j], 0, 0, 0);
    }
    __syncthreads();
  }

  const size_t zoff = (SPLITZ > 1 || DUALB) ? (size_t)z * (size_t)M * (size_t)N : 0;
#pragma unroll
  for (int i = 0; i < 4; ++i) {
#pragma unroll
    for (int j = 0; j < 4; ++j) {
      const int col = bn * 128 + wc + j * 16 + lrow;
      if (col >= N) continue;
      const int row0 = bm * 128 + wr + i * 16 + kg * 4;
      float bv = 0.f;
      if (BIAS) bv = bias[col];
#pragma unroll
      for (int rr = 0; rr < 4; ++rr) {
        const int gr = row0 + rr;
        if (gr < M) {
          const float v = acc[i][j][rr] + bv;
          if constexpr (std::is_same<OutT, __half>::value)
            C[zoff + (size_t)gr * (size_t)N + col] = __float2half(v);
          else
            C[zoff + (size_t)gr * (size_t)N + col] = v;
        }
      }
    }
  }
}

// ---------------- fp32 -> bf16 convert (8 elems/thread)
__global__ __launch_bounds__(256) void f2b(
    const float4* __restrict__ in, u32x4* __restrict__ out, int n8)
{
  const int i = blockIdx.x * 256 + threadIdx.x;
  if (i < n8) {
    const float4 a = in[2 * i], b = in[2 * i + 1];
    u32x4 o = { pack_bf16(a.x, a.y), pack_bf16(a.z, a.w),
                pack_bf16(b.x, b.y), pack_bf16(b.z, b.w) };
    out[i] = o;
  }
}

// ---------------- fused: sum split-K partials + bias + LayerNorm + exact GELU + l2norm
__global__ __launch_bounds__(256) void gee_fuse_ln1(
    const float* __restrict__ P, const float* __restrict__ b_enc,
    const float* __restrict__ g1, const float* __restrict__ b1,
    float* __restrict__ hx)
{
  const int row = blockIdx.x, tid = threadIdx.x;
  __shared__ float red[16];
  const size_t MN = (size_t)4096 * 512;
  float v[2];
#pragma unroll
  for (int e = 0; e < 2; ++e) {
    const int c = tid + e * 256;
    const size_t o = (size_t)row * 512 + c;
    v[e] = P[o] + P[MN + o] + P[2 * MN + o] + P[3 * MN + o] + b_enc[c];
  }
  float a = v[0] + v[1];
  float b = v[0] * v[0] + v[1] * v[1];
#pragma unroll
  for (int o = 32; o > 0; o >>= 1) { a += __shfl_xor(a, o); b += __shfl_xor(b, o); }
  const int lane = tid & 63, wvi = tid >> 6;
  if (lane == 0) { red[wvi] = a; red[8 + wvi] = b; }
  __syncthreads();
  const float mu  = (red[0] + red[1] + red[2] + red[3]) * (1.f / 512.f);
  const float ex2 = (red[8] + red[9] + red[10] + red[11]) * (1.f / 512.f);
  const float inv = rsqrtf(ex2 - mu * mu + 1e-5f);
  float gl[2], ss = 0.f;
#pragma unroll
  for (int e = 0; e < 2; ++e) {
    const int c = tid + e * 256;
    const float y = (v[e] - mu) * inv * g1[c] + b1[c];
    const float t = 0.5f * y * (1.f + erff(y * 0.70710678118654752f));
    gl[e] = t; ss += t * t;
  }
  __syncthreads();
#pragma unroll
  for (int o = 32; o > 0; o >>= 1) ss += __shfl_xor(ss, o);
  if (lane == 0) red[wvi] = ss;
  __syncthreads();
  const float nrm = sqrtf(red[0] + red[1] + red[2] + red[3]);
  const float sc = 1.f / fmaxf(nrm, 1e-12f);
#pragma unroll
  for (int e = 0; e < 2; ++e)
    hx[(size_t)row * 512 + tid + e * 256] = gl[e] * sc;
}

// ---------------- row l2norm of raw e [20000,512] fp32 -> eb bf16
__global__ __launch_bounds__(256) void gee_l2rows(
    const float* __restrict__ ein, ushort_t* __restrict__ eb)
{
  const int row = blockIdx.x, tid = threadIdx.x;
  __shared__ float red[4];
  const float2* er = (const float2*)(ein + (size_t)row * 512);
  const float2 v = er[tid];
  float ss = v.x * v.x + v.y * v.y;
#pragma unroll
  for (int o = 32; o > 0; o >>= 1) ss += __shfl_xor(ss, o);
  if ((tid & 63) == 0) red[tid >> 6] = ss;
  __syncthreads();
  const float sc = 1.f / fmaxf(sqrtf(red[0] + red[1] + red[2] + red[3]), 1e-12f);
  ((unsigned int*)eb)[(size_t)row * 256 + tid] = pack_bf16(v.x * sc, v.y * sc);
}

// ---------------- per-row top-64: LDS byte-histogram select + compaction
__global__ __launch_bounds__(256) void gee_topk(
    const __half* __restrict__ scores, int* __restrict__ oidx, float* __restrict__ ow)
{
  constexpr int G = 20000, GP = G / 2, CAP = 2048, TCAP = 160;
  const int row = blockIdx.x, tid = threadIdx.x;
  const int lane = tid & 63, wv = tid >> 6;
  __shared__ int hist[4][256];
  __shared__ int cnt_ge[256];
  __shared__ int wtop[4];
  __shared__ unsigned int comp[CAP];   // (key<<16) | idx
  __shared__ int whist[4][16];
  __shared__ int sel[64];
  __shared__ int tie[TCAP];
  __shared__ int s_thr, s_above, s_cand, s_cnt, s_n1, s_n2;

  const unsigned int* srow32 =
      (const unsigned int*)((const ushort_t*)scores + (size_t)row * G);
  const ushort_t* srow16 = (const ushort_t*)srow32;

#pragma unroll
  for (int b = 0; b < 4; ++b) hist[b][tid] = 0;
  if (tid == 0) { s_cnt = 0; s_n1 = 0; s_n2 = 0; }
  __syncthreads();

  // ---- scan 1: per-wave-privatized 256-bin histogram of the top key byte
  for (int j0 = 0; j0 < GP; j0 += 256) {
    const int j = j0 + tid;
    if (j < GP) {
      const unsigned int p = srow32[j];
      // packed monotone map: per half, key = raw ^ (0x8000 + sign*0x7FFF)
      const unsigned int f = (((p >> 15) & 0x10001u) * 0x7FFFu) + 0x80008000u;
      const unsigned int k2 = p ^ f;
      atomicAdd(&hist[wv][(k2 >> 8) & 0xFFu], 1);
      atomicAdd(&hist[wv][k2 >> 24], 1);
    }
  }
  __syncthreads();
  // total per byte, then suffix-sum (Hillis-Steele): cnt_ge[b] = #elems with byte >= b
  cnt_ge[tid] = hist[0][tid] + hist[1][tid] + hist[2][tid] + hist[3][tid];
  __syncthreads();
  for (int off = 1; off < 256; off <<= 1) {
    const int add = (tid + off < 256) ? cnt_ge[tid + off] : 0;
    __syncthreads();
    cnt_ge[tid] += add;
    __syncthreads();
  }
  // threshold byte = largest b with cnt_ge[b] >= 64 (cnt_ge is non-increasing)
  {
    const unsigned long long m = __ballot(cnt_ge[tid] >= 64);
    if (lane == 0) wtop[wv] = m ? (wv * 64 + 63 - __clzll(m)) : -1;
  }
  __syncthreads();
  if (tid == 0) {
    const int thrB = max(max(wtop[0], wtop[1]), max(wtop[2], wtop[3]));
    s_cand  = cnt_ge[thrB];
    s_above = (thrB == 255) ? 0 : cnt_ge[thrB + 1];
    s_thr   = thrB << 8;
  }
  __syncthreads();

  const bool useComp = (s_cand <= CAP);
  const unsigned int thrB = ((unsigned int)s_thr) >> 8;

  // ---- scan 2: compact elements with byte >= thrB (exactly s_cand of them)
  if (useComp) {
    for (int j0 = 0; j0 < GP; j0 += 256) {
      const int j = j0 + tid;
      if (j < GP) {
        const unsigned int p = srow32[j];
        const unsigned int f = (((p >> 15) & 0x10001u) * 0x7FFFu) + 0x80008000u;
        const unsigned int k2 = p ^ f;
        const unsigned int lo = k2 & 0xFFFFu, hi = k2 >> 16;
        if ((lo >> 8) >= thrB) {
          const int pos = atomicAdd(&s_cnt, 1);
          comp[pos] = (lo << 16) | (unsigned)(2 * j);
        }
        if ((hi >> 8) >= thrB) {
          const int pos = atomicAdd(&s_cnt, 1);
          comp[pos] = (hi << 16) | (unsigned)(2 * j + 1);
        }
      }
    }
  }
  __syncthreads();
  const int Nloop = useComp ? s_cnt : G;

  // ---- nibble passes over compact list (or global fallback): bits [7:4], [3:0]
  for (int pass = 2; pass < 4; ++pass) {
    const int shift = 12 - 4 * pass;
    const unsigned int thr = (unsigned int)s_thr;
    const unsigned int pfx = thr >> (shift + 4);
    int c[16];
#pragma unroll
    for (int b = 0; b < 16; ++b) c[b] = 0;
    for (int j0 = 0; j0 < Nloop; j0 += 256) {
      const int j = j0 + tid;
      const bool ok = j < Nloop;
      unsigned int key;
      if (useComp) {
        key = ok ? (comp[j] >> 16) : 0u;
      } else {
        const unsigned int raw = ok ? (unsigned int)srow16[j] : 0u;
        key = (raw & 0x8000u) ? (0xFFFFu & ~raw) : (raw | 0x8000u);
      }
      const unsigned int nb = (ok && (key >> (shift + 4)) == pfx) ? ((key >> shift) & 15u) : 0xFFu;
#pragma unroll
      for (int b = 0; b < 16; ++b) c[b] += __popcll(__ballot(nb == (unsigned)b));
    }
    if (lane == 0) {
#pragma unroll
      for (int b = 0; b < 16; ++b) whist[wv][b] = c[b];
    }
    __syncthreads();
    if (tid == 0) {
      int run = s_above;
      for (int vv = 15; vv >= 0; --vv) {
        const int c4 = whist[0][vv] + whist[1][vv] + whist[2][vv] + whist[3][vv];
        if (run + c4 >= 64) { s_thr |= vv << shift; break; }
        run += c4;
      }
      s_above = run;
    }
    __syncthreads();
  }

  // ---- selection: key > kthr -> sel, == kthr -> tie
  const unsigned int kthr = (unsigned int)s_thr;
  for (int j0 = 0; j0 < Nloop; j0 += 256) {
    const int j = j0 + tid;
    if (j < Nloop) {
      unsigned int key, idx;
      if (useComp) {
        const unsigned int u = comp[j];
        key = u >> 16; idx = u & 0xFFFFu;
      } else {
        const unsigned int raw = (unsigned int)srow16[j];
        key = (raw & 0x8000u) ? (0xFFFFu & ~raw) : (raw | 0x8000u);
        idx = (unsigned)j;
      }
      if (key > kthr) {
        const int pos = atomicAdd(&s_n1, 1);
        sel[pos] = (int)idx;
      } else if (key == kthr) {
        const int pos = atomicAdd(&s_n2, 1);
        if (pos < TCAP) tie[pos] = (int)idx;
      }
    }
  }
  __syncthreads();
  if (tid == 0) {
    const int n1 = s_n1;
    const int n2 = min(s_n2, TCAP);
    const int need = 64 - n1;
    for (int rr = 0; rr < need; ++rr) {     // smallest indices (top_k tie-break)
      int best = 1 << 30, bj = 0;
      for (int j = 0; j < n2; ++j)
        if (tie[j] < best) { best = tie[j]; bj = j; }
      sel[n1 + rr] = best;
      tie[bj] = 1 << 30;
    }
  }
  __syncthreads();
  if (tid < 64) {
    const int idx = sel[tid];
    const float s = __half2float(scores[(size_t)row * G + idx]) * 10.0f;  // 1/T
    float m = s;
#pragma unroll
    for (int o = 32; o > 0; o >>= 1) m = fmaxf(m, __shfl_xor(m, o));
    const float w = __expf(s - m);
    float d = w;
#pragma unroll
    for (int o = 32; o > 0; o >>= 1) d += __shfl_xor(d, o);
    oidx[(size_t)row * 64 + tid] = idx;
    ow[(size_t)row * 64 + tid] = w / d;
  }
}

// ---------------- ctx[b] = sum_k attn_k * eb[idx_k]  (bf16 gather, fp32 accum)
__global__ __launch_bounds__(256) void gee_ctx(
    const int* __restrict__ idx, const float* __restrict__ w,
    const ushort_t* __restrict__ eb, float* __restrict__ ctx)
{
  const int row = blockIdx.x, tid = threadIdx.x;
  __shared__ int sidx[64];
  __shared__ float sw[64];
  if (tid < 64) { sidx[tid] = idx[(size_t)row * 64 + tid]; sw[tid] = w[(size_t)row * 64 + tid]; }
  __syncthreads();
  float a0 = 0.f, a1 = 0.f;
#pragma unroll 4
  for (int k = 0; k < 64; ++k) {
    const unsigned int pk = ((const unsigned int*)(eb + (size_t)sidx[k] * 512))[tid];
    const float wk = sw[k];
    a0 += wk * __uint_as_float(pk << 16);
    a1 += wk * __uint_as_float(pk & 0xFFFF0000u);
  }
  ((float2*)(ctx + (size_t)row * 512))[tid] = make_float2(a0, a1);
}

// ---------------- h_cell = (1+gamma)*h_x + beta
__global__ __launch_bounds__(256) void gee_film(
    const float4* __restrict__ gm, const float4* __restrict__ bt,
    const float4* __restrict__ hx, float4* __restrict__ hc, int n4)
{
  const int i = blockIdx.x * 256 + threadIdx.x;
  if (i < n4) {
    const float4 g = gm[i], b = bt[i], h = hx[i];
    float4 r;
    r.x = (1.f + g.x) * h.x + b.x;
    r.y = (1.f + g.y) * h.y + b.y;
    r.z = (1.f + g.z) * h.z + b.z;
    r.w = (1.f + g.w) * h.w + b.w;
    hc[i] = r;
  }
}

// ---------------- LN2 + exact GELU -> out [4096,1024]
__global__ __launch_bounds__(256) void gee_ln2(
    const float* __restrict__ h2, const float* __restrict__ g2,
    const float* __restrict__ b2, float* __restrict__ out)
{
  const int row = blockIdx.x, tid = threadIdx.x;
  __shared__ float red[16];
  float v[4];
  float a = 0.f, b = 0.f;
#pragma unroll
  for (int e = 0; e < 4; ++e) {
    v[e] = h2[(size_t)row * 1024 + tid + e * 256];
    a += v[e]; b += v[e] * v[e];
  }
#pragma unroll
  for (int o = 32; o > 0; o >>= 1) { a += __shfl_xor(a, o); b += __shfl_xor(b, o); }
  const int lane = tid & 63, wvi = tid >> 6;
  if (lane == 0) { red[wvi] = a; red[8 + wvi] = b; }
  __syncthreads();
  const float mu  = (red[0] + red[1] + red[2] + red[3]) * (1.f / 1024.f);
  const float ex2 = (red[8] + red[9] + red[10] + red[11]) * (1.f / 1024.f);
  const float inv = rsqrtf(ex2 - mu * mu + 1e-5f);
#pragma unroll
  for (int e = 0; e < 4; ++e) {
    const int c = tid + e * 256;
    const float y = (v[e] - mu) * inv * g2[c] + b2[c];
    out[(size_t)row * 1024 + c] = 0.5f * y * (1.f + erff(y * 0.70710678118654752f));
  }
}

extern "C" void kernel_launch(void* const* d_in, const int* in_sizes, int n_in,
                              void* d_out, int out_size, void* d_ws, size_t ws_size,
                              hipStream_t stream)
{
  const float* x       = (const float*)d_in[0];
  const float* g       = (const float*)d_in[1];
  const float* W_enc   = (const float*)d_in[2];
  const float* b_enc   = (const float*)d_in[3];
  const float* ln1_g   = (const float*)d_in[4];
  const float* ln1_b   = (const float*)d_in[5];
  const float* W_ga    = (const float*)d_in[6];
  const float* W_gamma = (const float*)d_in[7];
  const float* b_gamma = (const float*)d_in[8];
  const float* W_beta  = (const float*)d_in[9];
  const float* b_beta  = (const float*)d_in[10];
  const float* W_exp   = (const float*)d_in[11];
  const float* b_exp   = (const float*)d_in[12];
  const float* ln2_g   = (const float*)d_in[13];
  const float* ln2_b   = (const float*)d_in[14];
  float* out = (float*)d_out;

  char* ws = (char*)d_ws;
  constexpr size_t OFF_PART   = 0;            // 33,554,432
  constexpr size_t OFF_SCORES = 0;            // 163,840,000
  constexpr size_t OFF_GA     = 0;            // 8,388,608
  constexpr size_t OFF_BE     = 8388608;      // 8,388,608  (GA + M*N*4 for DUALB)
  constexpr size_t OFF_HC     = 16777216;     // 8,388,608
  constexpr size_t OFF_H2     = 25165824;     // 16,777,216
  constexpr size_t OFF_CTX    = 50331648;     // 8,388,608
  constexpr size_t OFF_WENCB  = 163840000;    // 20,480,000 (also eb later)
  constexpr size_t OFF_WGAB   = 184320000;    // 524,288
  constexpr size_t OFF_WGMB   = 184844288;    // 524,288
  constexpr size_t OFF_WBTB   = 185368576;    // 524,288
  constexpr size_t OFF_WEXB   = 185892864;    // 1,048,576
  constexpr size_t OFF_HX     = 186941440;    // 8,388,608
  constexpr size_t OFF_E      = 195330048;    // 40,960,000
  constexpr size_t OFF_TIDX   = 236290048;    // 1,048,576
  constexpr size_t OFF_TW     = 237338624;    // 1,048,576  -> total 238,387,200

  float*    part   = (float*)(ws + OFF_PART);
  __half*   scores = (__half*)(ws + OFF_SCORES);
  float*    ga     = (float*)(ws + OFF_GA);
  float*    be     = (float*)(ws + OFF_BE);
  float*    hc     = (float*)(ws + OFF_HC);
  float*    h2     = (float*)(ws + OFF_H2);
  float*    ctx    = (float*)(ws + OFF_CTX);
  ushort_t* wencb  = (ushort_t*)(ws + OFF_WENCB);
  ushort_t* eb     = (ushort_t*)(ws + OFF_WENCB);   // time-shared with wencb
  ushort_t* wgab   = (ushort_t*)(ws + OFF_WGAB);
  ushort_t* wgmb   = (ushort_t*)(ws + OFF_WGMB);
  ushort_t* wbtb   = (ushort_t*)(ws + OFF_WBTB);
  ushort_t* wexb   = (ushort_t*)(ws + OFF_WEXB);
  float*    hx     = (float*)(ws + OFF_HX);
  float*    e      = (float*)(ws + OFF_E);
  int*      tidx   = (int*)(ws + OFF_TIDX);
  float*    tw     = (float*)(ws + OFF_TW);

  // 0) weight converts fp32 -> bf16
  f2b<<<5000, 256, 0, stream>>>((const float4*)W_enc,   (u32x4*)wencb, 1280000);
  f2b<<<128,  256, 0, stream>>>((const float4*)W_ga,    (u32x4*)wgab,  32768);
  f2b<<<128,  256, 0, stream>>>((const float4*)W_gamma, (u32x4*)wgmb,  32768);
  f2b<<<128,  256, 0, stream>>>((const float4*)W_beta,  (u32x4*)wbtb,  32768);
  f2b<<<256,  256, 0, stream>>>((const float4*)W_exp,   (u32x4*)wexb,  65536);

  // 1) split-K=4 partials of x @ W_enc^T  -> part[4][4096][512]
  bgemm<4, false, false, float><<<512, 256, 0, stream>>>(
      x, wencb, nullptr, nullptr, nullptr, part, 4096, 512, 20000, 4, 32);
  // 2) h_x = l2norm(gelu(LN1(sum partials + b_enc)))
  gee_fuse_ln1<<<4096, 256, 0, stream>>>(part, b_enc, ln1_g, ln1_b, hx);
  // 3) e_raw = g @ W_ga^T  [20000][512]
  bgemm<1, false, false, float><<<628, 256, 0, stream>>>(
      g, wgab, nullptr, nullptr, nullptr, e, 20000, 512, 512, 4, 157);
  // 4) eb = l2norm rows (bf16)
  gee_l2rows<<<20000, 256, 0, stream>>>(e, eb);
  // 5) scores = h_x @ eb^T  (fp16 raw cosine; /T applied in topk)
  bgemm<1, false, false, __half><<<5024, 256, 0, stream>>>(
      hx, eb, nullptr, nullptr, nullptr, scores, 4096, 20000, 512, 157, 32);
  // 6) top-64 + softmax weights
  gee_topk<<<4096, 256, 0, stream>>>(scores, tidx, tw);
  // 7) ctx = attn-weighted sum of eb rows
  gee_ctx<<<4096, 256, 0, stream>>>(tidx, tw, eb, ctx);
  // 8) FiLM gamma (z=0) / beta (z=1) in one launch
  bgemm<1, true, true, float><<<256, 256, 0, stream>>>(
      ctx, wgmb, wbtb, b_gamma, b_beta, ga, 4096, 512, 512, 4, 32);
  // 9) h_cell = (1+gamma)*h_x + beta
  gee_film<<<2048, 256, 0, stream>>>((const float4*)ga, (const float4*)be,
                                     (const float4*)hx, (float4*)hc, 524288);
  // 10) h2 = h_cell @ W_exp^T + b_exp
  bgemm<1, false, true, float><<<256, 256, 0, stream>>>(
      hc, wexb, nullptr, b_exp, nullptr, h2, 4096, 1024, 512, 8, 32);
  // 11) out = gelu(LN2(h2))
  gee_ln2<<<4096, 256, 0, stream>>>(h2, ln2_g, ln2_b, out);
}